// Round 5
// baseline (139.670 us; speedup 1.0000x reference)
//
#include <hip/hip_runtime.h>
#include <math.h>

namespace {
constexpr int kB = 4;
constexpr int kL = 4096;
constexpr int kH = 16;
constexpr int kD = 64;
constexpr int kC = kH * kD;       // 1024 channels
constexpr int kM = 4096;          // complex FFT length (rfft of 8192 via packing)
constexpr int NTH = 256;

// ---------------- scalar complex helpers (aux kernels) ----------------
__device__ __forceinline__ float2 cmul(float2 a, float2 b) {
  return make_float2(a.x * b.x - a.y * b.y, a.x * b.y + a.y * b.x);
}
__device__ __forceinline__ float2 cadd(float2 a, float2 b) { return make_float2(a.x + b.x, a.y + b.y); }
__device__ __forceinline__ float2 csub(float2 a, float2 b) { return make_float2(a.x - b.x, a.y - b.y); }
__device__ __forceinline__ float2 cconj(float2 a) { return make_float2(a.x, -a.y); }
__device__ __forceinline__ float2 cmuli(float2 a) { return make_float2(-a.y, a.x); }  // i*a
__device__ __forceinline__ float2 cscale(float2 a, float s) { return make_float2(a.x * s, a.y * s); }

// ---------------- packed-FP32 complex helpers (fft_rows) ----------------
typedef float cplx __attribute__((ext_vector_type(2)));
typedef float cplx2 __attribute__((ext_vector_type(4)));

__device__ __forceinline__ cplx pk_add(cplx a, cplx b) {
  cplx r;
  asm("v_pk_add_f32 %0, %1, %2" : "=v"(r) : "v"(a), "v"(b));
  return r;
}
__device__ __forceinline__ cplx pk_sub(cplx a, cplx b) {
  cplx r;
  asm("v_pk_add_f32 %0, %1, %2 neg_lo:[0,1] neg_hi:[0,1]" : "=v"(r) : "v"(a), "v"(b));
  return r;
}
// a + i*b = (a.x - b.y, a.y + b.x)
__device__ __forceinline__ cplx pk_addpi(cplx a, cplx b) {
  cplx r;
  asm("v_pk_add_f32 %0, %1, %2 op_sel:[0,1] op_sel_hi:[1,0] neg_lo:[0,1]" : "=v"(r) : "v"(a), "v"(b));
  return r;
}
// a - i*b = (a.x + b.y, a.y - b.x)
__device__ __forceinline__ cplx pk_addmi(cplx a, cplx b) {
  cplx r;
  asm("v_pk_add_f32 %0, %1, %2 op_sel:[0,1] op_sel_hi:[1,0] neg_hi:[0,1]" : "=v"(r) : "v"(a), "v"(b));
  return r;
}
// complex multiply: 2 VOP3P ops
__device__ __forceinline__ cplx pk_cmul(cplx a, cplx b) {
  cplx t, r;
  asm("v_pk_mul_f32 %0, %1, %2 op_sel:[0,0] op_sel_hi:[0,1]" : "=v"(t) : "v"(a), "v"(b));
  asm("v_pk_fma_f32 %0, %1, %2, %3 op_sel:[1,1,0] op_sel_hi:[1,0,1] neg_lo:[0,1,0]"
      : "=v"(r) : "v"(a), "v"(b), "v"(t));
  return r;
}

// base-4 digit reversal of a 12-bit index (fallback kernel only)
__device__ __forceinline__ unsigned dr4(unsigned p) {
  unsigned r = __brev(p) >> 20;
  return ((r & 0x555u) << 1) | ((r >> 1) & 0x555u);
}
// base-16 digit reversal of a 12-bit index (involution)
__device__ __forceinline__ unsigned dr16(unsigned p) {
  return ((p & 15u) << 8) | (p & 0xF0u) | (p >> 8);
}
// additive affine LDS pad (cplx index space): digit (g,s,u) -> 288g + 18s + u.
// Contiguous 16-runs stay contiguous & 16B-aligned (b128-able); strides 16->18,
// 256->288 are <=2-way bank aliased per 16-lane group (free).
__device__ __forceinline__ int AD(int i) { return i + 2 * (i >> 4); }
constexpr int kZPadA = 4606;  // AD(4095)+1 cplx = 36848 B

// after in-register DFT16, X[k] lives at register slot POS(k)
#define POS(k) ((((k) & 3) << 2) | ((k) >> 2))

// fallback-kernel padding
__device__ __forceinline__ int IDX(int i) { return i + (i >> 4); }
constexpr int kZPad = kM + (kM >> 4);

// depth-4 twiddle power tree: W1..W15 = w^1..w^15
#define TW_TREE(w)                                                            \
  cplx W1 = (w), W2 = pk_cmul(W1, W1), W4 = pk_cmul(W2, W2),                  \
       W8 = pk_cmul(W4, W4);                                                  \
  cplx W3 = pk_cmul(W2, W1), W5 = pk_cmul(W4, W1), W6 = pk_cmul(W4, W2),      \
       W7 = pk_cmul(W4, W3);                                                  \
  cplx W9 = pk_cmul(W8, W1), W10 = pk_cmul(W8, W2), W11 = pk_cmul(W8, W3),    \
       W12 = pk_cmul(W8, W4);                                                 \
  cplx W13 = pk_cmul(W8, W5), W14 = pk_cmul(W8, W6), W15 = pk_cmul(W8, W7);

#define TW_APPLY(r)                                                           \
  r[POS(1)] = pk_cmul(r[POS(1)], W1);   r[POS(2)] = pk_cmul(r[POS(2)], W2);   \
  r[POS(3)] = pk_cmul(r[POS(3)], W3);   r[POS(4)] = pk_cmul(r[POS(4)], W4);   \
  r[POS(5)] = pk_cmul(r[POS(5)], W5);   r[POS(6)] = pk_cmul(r[POS(6)], W6);   \
  r[POS(7)] = pk_cmul(r[POS(7)], W7);   r[POS(8)] = pk_cmul(r[POS(8)], W8);   \
  r[POS(9)] = pk_cmul(r[POS(9)], W9);   r[POS(10)] = pk_cmul(r[POS(10)], W10);\
  r[POS(11)] = pk_cmul(r[POS(11)], W11); r[POS(12)] = pk_cmul(r[POS(12)], W12);\
  r[POS(13)] = pk_cmul(r[POS(13)], W13); r[POS(14)] = pk_cmul(r[POS(14)], W14);\
  r[POS(15)] = pk_cmul(r[POS(15)], W15);

// shifted tree: B[k] = b0 * w^k, k = 0..15, depth ~4
#define TWS_TREE(b0, w)                                                       \
  cplx P2 = pk_cmul(w, w), P4 = pk_cmul(P2, P2), P8 = pk_cmul(P4, P4);        \
  cplx B0 = (b0), B1 = pk_cmul(b0, w), B2 = pk_cmul(B0, P2),                  \
       B3 = pk_cmul(B1, P2);                                                  \
  cplx B4 = pk_cmul(B0, P4), B5 = pk_cmul(B1, P4), B6 = pk_cmul(B2, P4),      \
       B7 = pk_cmul(B3, P4);                                                  \
  cplx B8 = pk_cmul(B0, P8), B9 = pk_cmul(B1, P8), B10 = pk_cmul(B2, P8),     \
       B11 = pk_cmul(B3, P8);                                                 \
  cplx B12 = pk_cmul(B4, P8), B13 = pk_cmul(B5, P8), B14 = pk_cmul(B6, P8),   \
       B15 = pk_cmul(B7, P8);

#define TWS_APPLY(r)                                                          \
  r[POS(0)] = pk_cmul(r[POS(0)], B0);   r[POS(1)] = pk_cmul(r[POS(1)], B1);   \
  r[POS(2)] = pk_cmul(r[POS(2)], B2);   r[POS(3)] = pk_cmul(r[POS(3)], B3);   \
  r[POS(4)] = pk_cmul(r[POS(4)], B4);   r[POS(5)] = pk_cmul(r[POS(5)], B5);   \
  r[POS(6)] = pk_cmul(r[POS(6)], B6);   r[POS(7)] = pk_cmul(r[POS(7)], B7);   \
  r[POS(8)] = pk_cmul(r[POS(8)], B8);   r[POS(9)] = pk_cmul(r[POS(9)], B9);   \
  r[POS(10)] = pk_cmul(r[POS(10)], B10); r[POS(11)] = pk_cmul(r[POS(11)], B11);\
  r[POS(12)] = pk_cmul(r[POS(12)], B12); r[POS(13)] = pk_cmul(r[POS(13)], B13);\
  r[POS(14)] = pk_cmul(r[POS(14)], B14); r[POS(15)] = pk_cmul(r[POS(15)], B15);

// filt[k] = amp * (1 + i k)^(-dec), with 1/M ifft scale folded into ampS
__device__ __forceinline__ float2 filt_val(float k, float ampS, float dec) {
  float mag = ampS * __expf(-0.5f * dec * log1pf(k * k));
  float ph = -dec * atanf(k);
  float s, c;
  __sincosf(ph, &s, &c);
  return make_float2(mag * c, mag * s);
}

// ---- fully-unrolled 16-point DFT in registers (packed-FP32) ----
// S = -1 forward, +1 inverse (unnormalized). HZ: inputs r[8..15] treated as 0.
// Output X[k] at slot POS(k).
template <int S, bool HZ>
__device__ __forceinline__ void fft16(cplx r[16]) {
  constexpr float C1 = 0.92387953251128674f;
  constexpr float S1 = 0.38268343236508978f;
  constexpr float R2 = 0.70710678118654752f;
  const float sg = (float)S;
  const cplx Wa = {C1, sg * S1};
  const cplx Wb = {R2, sg * R2};
  const cplx Wc = {S1, sg * C1};
  const cplx Wd = {-R2, sg * R2};
  const cplx We = {-C1, -sg * S1};
#pragma unroll
  for (int n2 = 0; n2 < 4; ++n2) {
    cplx t0, t1, t2, t3;
    if (HZ) {
      t0 = r[n2]; t1 = r[n2]; t2 = r[n2 + 4]; t3 = r[n2 + 4];
    } else {
      cplx a0 = r[n2], a1 = r[n2 + 4], a2 = r[n2 + 8], a3 = r[n2 + 12];
      t0 = pk_add(a0, a2); t1 = pk_sub(a0, a2); t2 = pk_add(a1, a3); t3 = pk_sub(a1, a3);
    }
    cplx u0 = pk_add(t0, t2);
    cplx u2 = pk_sub(t0, t2);
    cplx u1 = (S < 0) ? pk_addmi(t1, t3) : pk_addpi(t1, t3);
    cplx u3 = (S < 0) ? pk_addpi(t1, t3) : pk_addmi(t1, t3);
    if (n2 == 0) { r[0] = u0; r[4] = u1; r[8] = u2; r[12] = u3; }
    if (n2 == 1) { r[1] = u0; r[5] = pk_cmul(u1, Wa); r[9] = pk_cmul(u2, Wb); r[13] = pk_cmul(u3, Wc); }
    if (n2 == 2) {
      r[2] = u0; r[6] = pk_cmul(u1, Wb);
      cplx m;
      if (S < 0) { m.x = u2.y; m.y = -u2.x; } else { m.x = -u2.y; m.y = u2.x; }
      r[10] = m;
      r[14] = pk_cmul(u3, Wd);
    }
    if (n2 == 3) { r[3] = u0; r[7] = pk_cmul(u1, Wc); r[11] = pk_cmul(u2, Wd); r[15] = pk_cmul(u3, We); }
  }
#pragma unroll
  for (int s = 0; s < 4; ++s) {
    cplx b0 = r[4 * s], b1 = r[4 * s + 1], b2 = r[4 * s + 2], b3 = r[4 * s + 3];
    cplx t0 = pk_add(b0, b2), t1 = pk_sub(b0, b2), t2 = pk_add(b1, b3), t3 = pk_sub(b1, b3);
    r[4 * s] = pk_add(t0, t2);
    r[4 * s + 2] = pk_sub(t0, t2);
    r[4 * s + 1] = (S < 0) ? pk_addmi(t1, t3) : pk_addpi(t1, t3);
    r[4 * s + 3] = (S < 0) ? pk_addpi(t1, t3) : pk_addmi(t1, t3);
  }
}

// pointwise pair map (verified algebra), used only by build_table
__device__ __forceinline__ void pw_pair(float2 Zk, float2 Zmk, int k, float ampS, float dec,
                                        float2* Wk, float2* Wmk) {
  float2 A = cscale(cadd(Zk, cconj(Zmk)), 0.5f);
  float2 Bv = cscale(csub(Zk, cconj(Zmk)), 0.5f);
  float sn, cs;
  __sincosf(-3.14159265358979323846f * (float)k / (float)kM, &sn, &cs);
  float2 tw = make_float2(cs, sn);
  float2 P = cmuli(cmul(tw, Bv));
  float2 Xk = csub(A, P);
  float2 Xmk = cconj(cadd(A, P));
  float2 Yk = cmul(Xk, filt_val((float)k, ampS, dec));
  float2 Ymk = cmul(Xmk, filt_val((float)(kM - k), ampS, dec));
  float2 Ev = cscale(cadd(Yk, cconj(Ymk)), 0.5f);
  float2 Ov = cscale(cmul(cconj(tw), csub(Yk, cconj(Ymk))), 0.5f);
  float2 iO = cmuli(Ov);
  *Wk = cadd(Ev, iO);
  *Wmk = cconj(csub(Ev, iO));
}
}  // namespace

// ---------- pass 0: per-(h,k) 2x2 complex coefficient table ----------
__global__ __launch_bounds__(256) void build_table(const float* __restrict__ la,
                                                   const float* __restrict__ ld,
                                                   float2* __restrict__ tab) {
  int k = blockIdx.x * 256 + threadIdx.x;  // 0..2047
  int h = blockIdx.y;
  float av = la[h], dv = ld[h];
  float amp = (av > 20.f) ? av : log1pf(__expf(av));
  float dec = ((dv > 20.f) ? dv : log1pf(__expf(dv))) + 1e-4f;
  float ampS = amp * (1.0f / (float)kM);
  float2* e = tab + ((size_t)h * 2048 + k) * 4;
  if (k == 0) {
    float F0 = filt_val(0.f, ampS, dec).x;
    float FM = filt_val((float)kM, ampS, dec).x;
    e[0] = make_float2(0.5f * (F0 + FM), 0.5f * (F0 - FM));
    e[1] = make_float2(0.5f * (F0 - FM), 0.5f * (F0 + FM));
    e[2] = cconj(filt_val((float)(kM / 2), ampS, dec));
    e[3] = make_float2(0.f, 0.f);
  } else {
    float2 a, b, g, d;
    pw_pair(make_float2(1.f, 0.f), make_float2(0.f, 0.f), k, ampS, dec, &a, &g);
    pw_pair(make_float2(0.f, 0.f), make_float2(1.f, 0.f), k, ampS, dec, &b, &d);
    e[0] = a; e[1] = b; e[2] = g; e[3] = d;
  }
}

// ---------- pass 1: transpose x (B, L, C) -> ws (B, C, L), coalesced ----------
__global__ __launch_bounds__(256) void transpose_fwd(const float* __restrict__ in,
                                                     float* __restrict__ outp) {
  __shared__ float T[32][33];
  const int b = blockIdx.z;
  const int r0 = blockIdx.x * 32;  // l
  const int c0 = blockIdx.y * 32;  // c
  const float* ib = in + (size_t)b * kL * kC;
  float* ob = outp + (size_t)b * kC * kL;
  const int tx = threadIdx.x & 31, ty = threadIdx.x >> 5;
  for (int i = 0; i < 32; i += 8)
    T[ty + i][tx] = ib[(size_t)(r0 + ty + i) * kC + c0 + tx];
  __syncthreads();
  for (int i = 0; i < 32; i += 8)
    ob[(size_t)(c0 + ty + i) * kL + r0 + tx] = T[tx][ty + i];
}

// ---------- pass 2: per-row FFT conv (16^3 register radix-16, packed math) ----------
__global__ __launch_bounds__(NTH, 4) void fft_rows(float* __restrict__ ws,
                                                   const float2* __restrict__ tab) {
  __shared__ __align__(16) cplx Z[kZPadA];  // 36848 B, 4 blocks/CU
  const int row = blockIdx.x;  // b*1024 + c
  const int h = (row >> 6) & (kH - 1);
  const int t = threadIdx.x;
  cplx* xrow = (cplx*)(ws + (size_t)row * kL);  // 2048 cplx

  cplx r[16];
  const int b3 = 18 * (t >> 4) + (t & 15);  // affine base for F1-store / I3-read

  // ---- F1: global load (coalesced), DFT16 over n1, twiddle W4096^{t*k1} ----
#pragma unroll
  for (int j = 0; j < 8; ++j) r[j] = xrow[t + 256 * j];
  fft16<-1, true>(r);
  {
    float sn, cs;
    __sincosf(-6.283185307179586f * (float)t / 4096.f, &sn, &cs);
    cplx w = {cs, sn};
    TW_TREE(w);
    TW_APPLY(r);
#pragma unroll
    for (int k1 = 0; k1 < 16; ++k1) Z[b3 + 288 * k1] = r[POS(k1)];
  }
  __syncthreads();

  // ---- F2: DFT16 over m1 (stride 18 phys), twiddle W256^{m2*j1} ----
  {
    const int base = 288 * (t >> 4) + (t & 15);
    const int m2 = t & 15;
#pragma unroll
    for (int m1 = 0; m1 < 16; ++m1) r[m1] = Z[base + 18 * m1];
    fft16<-1, false>(r);
    float sn, cs;
    __sincosf(-6.283185307179586f * (float)m2 / 256.f, &sn, &cs);
    cplx w = {cs, sn};
    TW_TREE(w);
    TW_APPLY(r);
#pragma unroll
    for (int j1 = 0; j1 < 16; ++j1) Z[base + 18 * j1] = r[POS(j1)];
  }
  __syncthreads();

  // ---- F3: DFT16 over m2 (contiguous 16, b128), no twiddle ----
  {
    cplx2* Zv = (cplx2*)&Z[288 * (t >> 4) + 18 * (t & 15)];
#pragma unroll
    for (int j = 0; j < 8; ++j) {
      cplx2 q = Zv[j];
      r[2 * j].x = q.x; r[2 * j].y = q.y;
      r[2 * j + 1].x = q.z; r[2 * j + 1].y = q.w;
    }
    fft16<-1, false>(r);
#pragma unroll
    for (int j = 0; j < 8; ++j) {
      cplx a = r[POS(2 * j)], b = r[POS(2 * j + 1)];
      cplx2 q; q.x = a.x; q.y = a.y; q.z = b.x; q.w = b.y;
      Zv[j] = q;
    }
  }
  __syncthreads();

  // ---- pointwise via table; position p holds bin dr16(p); 8 tight iters ----
  {
    const float4* tabh = (const float4*)(tab + (size_t)h * 2048 * 4);
#pragma unroll
    for (int i = 0; i < 8; ++i) {
      int k = t + (i << 8);  // 0..2047
      if (k == 0) {
        float4 q0 = tabh[0];
        cplx Z0 = Z[0];
        cplx o; o.x = q0.x * Z0.x + q0.y * Z0.y; o.y = q0.z * Z0.x + q0.w * Z0.y;
        Z[0] = o;
        float4 q1 = tabh[1];
        cplx f; f.x = q1.x; f.y = q1.y;
        Z[8] = pk_cmul(f, Z[8]);  // p = dr16(2048) = 8, AD(8) = 8
      } else {
        int p = (int)dr16((unsigned)k), p2 = (int)dr16(4096u - (unsigned)k);
        int sp = AD(p), sp2 = AD(p2);
        cplx Zk = Z[sp], Zmk = Z[sp2];
        float4 q0 = tabh[2 * k], q1 = tabh[2 * k + 1];
        cplx e0 = {q0.x, q0.y}, e1 = {q0.z, q0.w};
        cplx e2 = {q1.x, q1.y}, e3 = {q1.z, q1.w};
        cplx cZk = {Zk.x, -Zk.y}, cZmk = {Zmk.x, -Zmk.y};
        Z[sp] = pk_add(pk_cmul(e0, Zk), pk_cmul(e1, cZmk));
        Z[sp2] = pk_add(pk_cmul(e2, cZk), pk_cmul(e3, Zmk));
      }
    }
  }
  __syncthreads();

  // ---- I1: IDFT16 over j2 (contiguous 16, b128), twiddle e^{+2pi i j1*m2/256} ----
  {
    const int j1 = t & 15;
    cplx2* Zv = (cplx2*)&Z[288 * (t >> 4) + 18 * j1];
#pragma unroll
    for (int j = 0; j < 8; ++j) {
      cplx2 q = Zv[j];
      r[2 * j].x = q.x; r[2 * j].y = q.y;
      r[2 * j + 1].x = q.z; r[2 * j + 1].y = q.w;
    }
    fft16<1, false>(r);
    float sn, cs;
    __sincosf(6.283185307179586f * (float)j1 / 256.f, &sn, &cs);
    cplx w = {cs, sn};
    TW_TREE(w);
    TW_APPLY(r);
#pragma unroll
    for (int j = 0; j < 8; ++j) {
      cplx a = r[POS(2 * j)], b = r[POS(2 * j + 1)];
      cplx2 q; q.x = a.x; q.y = a.y; q.z = b.x; q.w = b.y;
      Zv[j] = q;
    }
  }
  __syncthreads();

  // ---- I2: IDFT16 over j1 (stride 18 phys), twiddle e^{+2pi i k1*(m1*16+m2)/4096} ----
  {
    const int k1 = t >> 4, m2 = t & 15;
    const int base = 288 * k1 + m2;
#pragma unroll
    for (int j1 = 0; j1 < 16; ++j1) r[j1] = Z[base + 18 * j1];
    fft16<1, false>(r);
    float sn, cs;
    __sincosf(6.283185307179586f * (float)(k1 * m2) / 4096.f, &sn, &cs);
    cplx b0 = {cs, sn};
    __sincosf(6.283185307179586f * (float)k1 / 256.f, &sn, &cs);
    cplx w = {cs, sn};
    TWS_TREE(b0, w);
    TWS_APPLY(r);
#pragma unroll
    for (int m1 = 0; m1 < 16; ++m1) Z[base + 18 * m1] = r[POS(m1)];
  }
  __syncthreads();

  // ---- I3: IDFT16 over k1 (stride 288 phys), direct coalesced global store ----
  {
#pragma unroll
    for (int k1 = 0; k1 < 16; ++k1) r[k1] = Z[b3 + 288 * k1];
    fft16<1, false>(r);
#pragma unroll
    for (int n1 = 0; n1 < 8; ++n1) xrow[(n1 << 8) + t] = r[POS(n1)];
  }
}

// ---------- pass 3: transpose back ws (B, C, L) -> out (B, L, C) + mix ----------
__global__ __launch_bounds__(256) void mix_out(const float* __restrict__ yT,
                                               const float* __restrict__ x,
                                               const float* __restrict__ mix_logit,
                                               float* __restrict__ outp) {
  __shared__ float T[32][33];
  const int b = blockIdx.z;
  const int r0 = blockIdx.x * 32;  // l
  const int c0 = blockIdx.y * 32;  // c
  const int h = c0 >> 6;
  const float ml = mix_logit[h];
  const float mix = 1.0f / (1.0f + __expf(-ml));
  const float omix = 1.0f - mix;
  const float* yb = yT + (size_t)b * kC * kL;
  const float* xb = x + (size_t)b * kL * kC;
  float* ob = outp + (size_t)b * kL * kC;
  const int tx = threadIdx.x & 31, ty = threadIdx.x >> 5;
  for (int i = 0; i < 32; i += 8)
    T[ty + i][tx] = yb[(size_t)(c0 + ty + i) * kL + r0 + tx];
  __syncthreads();
  for (int i = 0; i < 32; i += 8) {
    size_t idx = (size_t)(r0 + ty + i) * kC + c0 + tx;
    ob[idx] = mix * T[tx][ty + i] + omix * xb[idx];
  }
}

// ---------- fallback (round-1 single kernel) if ws is too small ----------
__global__ __launch_bounds__(NTH) void fftconv_fallback(
    const float* __restrict__ x, const float* __restrict__ log_amp,
    const float* __restrict__ log_decay, const float* __restrict__ mix_logit,
    float* __restrict__ out) {
  __shared__ float2 Z[kZPad];
  const int row = blockIdx.x;
  const int d = row & (kD - 1);
  const int h = (row >> 6) & (kH - 1);
  const int b = row >> 10;
  const int t = threadIdx.x;
  const size_t rowoff = (size_t)b * kL * kC + (size_t)h * kD + (size_t)d;
  const float* xrow = x + rowoff;
  float* orow = out + rowoff;

  const float av = log_amp[h];
  const float dv = log_decay[h];
  const float amp = (av > 20.f) ? av : log1pf(__expf(av));
  const float dec = ((dv > 20.f) ? dv : log1pf(__expf(dv))) + 1e-4f;
  const float ampS = amp * (1.0f / (float)kM);
  const float ml = mix_logit[h];
  const float mix = 1.0f / (1.0f + __expf(-ml));
  const float omix = 1.0f - mix;

  for (int i = 0; i < kM / NTH; ++i) {
    int n = t + i * NTH;
    float2 z;
    if (n < kL / 2) {
      z.x = xrow[(size_t)(2 * n) * kC];
      z.y = xrow[(size_t)(2 * n + 1) * kC];
    } else {
      z = make_float2(0.f, 0.f);
    }
    Z[IDX(n)] = z;
  }
  __syncthreads();

  for (int Ls = kM; Ls >= 4; Ls >>= 2) {
    const int q = Ls >> 2;
    const float wstep = -6.283185307179586f / (float)Ls;
    for (int i = 0; i < kM / 4 / NTH; ++i) {
      int bt = t + i * NTH;
      int jj = bt & (q - 1);
      int base = ((bt - jj) << 2) + jj;
      float2 a = Z[IDX(base)], bb = Z[IDX(base + q)];
      float2 c = Z[IDX(base + 2 * q)], dd = Z[IDX(base + 3 * q)];
      float2 t0 = cadd(a, c), t1 = csub(a, c), t2 = cadd(bb, dd), t3 = csub(bb, dd);
      float2 u0 = cadd(t0, t2), u2 = csub(t0, t2);
      float2 it3 = cmuli(t3);
      float2 u1 = csub(t1, it3), u3 = cadd(t1, it3);
      float sn, cs;
      __sincosf(wstep * (float)jj, &sn, &cs);
      float2 w1 = make_float2(cs, sn);
      float2 w2 = cmul(w1, w1);
      float2 w3 = cmul(w2, w1);
      Z[IDX(base)] = u0;
      Z[IDX(base + q)] = cmul(u1, w1);
      Z[IDX(base + 2 * q)] = cmul(u2, w2);
      Z[IDX(base + 3 * q)] = cmul(u3, w3);
    }
    __syncthreads();
  }

  for (int i = 0; i <= kM / 2 / NTH; ++i) {
    int k = t + i * NTH;
    if (k > kM / 2) continue;
    if (k == 0) {
      float2 Z0 = Z[IDX(0)];
      float X0 = Z0.x + Z0.y;
      float XM = Z0.x - Z0.y;
      float2 f0 = filt_val(0.f, ampS, dec);
      float2 fM = filt_val((float)kM, ampS, dec);
      float Y0 = X0 * f0.x;
      float YM = XM * fM.x;
      Z[IDX(0)] = make_float2(0.5f * (Y0 + YM), 0.5f * (Y0 - YM));
    } else if (k == kM / 2) {
      unsigned p = dr4(kM / 2);
      float2 Zk = Z[IDX(p)];
      float2 f = filt_val((float)(kM / 2), ampS, dec);
      float2 Y = cmul(cconj(Zk), f);
      Z[IDX(p)] = cconj(Y);
    } else {
      unsigned pk = dr4((unsigned)k), pmk = dr4((unsigned)(kM - k));
      float2 Zk = Z[IDX(pk)], Zmk = Z[IDX(pmk)];
      float2 A = cscale(cadd(Zk, cconj(Zmk)), 0.5f);
      float2 Bv = cscale(csub(Zk, cconj(Zmk)), 0.5f);
      float sn, cs;
      __sincosf(-3.14159265358979323846f * (float)k / (float)kM, &sn, &cs);
      float2 tw = make_float2(cs, sn);
      float2 P = cmuli(cmul(tw, Bv));
      float2 Xk = csub(A, P);
      float2 Xmk = cconj(cadd(A, P));
      float2 Yk = cmul(Xk, filt_val((float)k, ampS, dec));
      float2 Ymk = cmul(Xmk, filt_val((float)(kM - k), ampS, dec));
      float2 Ev = cscale(cadd(Yk, cconj(Ymk)), 0.5f);
      float2 Ov = cscale(cmul(cconj(tw), csub(Yk, cconj(Ymk))), 0.5f);
      float2 iO = cmuli(Ov);
      Z[IDX(pk)] = cadd(Ev, iO);
      Z[IDX(pmk)] = cconj(csub(Ev, iO));
    }
  }
  __syncthreads();

  for (int Ls = 4; Ls <= kM; Ls <<= 2) {
    const int q = Ls >> 2;
    const float wstep = 6.283185307179586f / (float)Ls;
    for (int i = 0; i < kM / 4 / NTH; ++i) {
      int bt = t + i * NTH;
      int jj = bt & (q - 1);
      int base = ((bt - jj) << 2) + jj;
      float sn, cs;
      __sincosf(wstep * (float)jj, &sn, &cs);
      float2 w1 = make_float2(cs, sn);
      float2 w2 = cmul(w1, w1);
      float2 w3 = cmul(w2, w1);
      float2 a = Z[IDX(base)];
      float2 bb = cmul(Z[IDX(base + q)], w1);
      float2 c = cmul(Z[IDX(base + 2 * q)], w2);
      float2 dd = cmul(Z[IDX(base + 3 * q)], w3);
      float2 s0 = cadd(a, c), s1 = csub(a, c), s2 = cadd(bb, dd), s3 = csub(bb, dd);
      float2 is3 = cmuli(s3);
      Z[IDX(base)] = cadd(s0, s2);
      Z[IDX(base + 2 * q)] = csub(s0, s2);
      Z[IDX(base + q)] = cadd(s1, is3);
      Z[IDX(base + 3 * q)] = csub(s1, is3);
    }
    __syncthreads();
  }

  for (int i = 0; i < kL / 2 / NTH; ++i) {
    int n = t + i * NTH;
    float2 w = Z[IDX(n)];
    size_t i0 = (size_t)(2 * n) * kC;
    float x0 = xrow[i0];
    float x1 = xrow[i0 + kC];
    orow[i0] = mix * w.x + omix * x0;
    orow[i0 + kC] = mix * w.y + omix * x1;
  }
}

extern "C" void kernel_launch(void* const* d_in, const int* in_sizes, int n_in,
                              void* d_out, int out_size, void* d_ws, size_t ws_size,
                              hipStream_t stream) {
  const float* x = (const float*)d_in[0];
  const float* la = (const float*)d_in[1];
  const float* ld = (const float*)d_in[2];
  const float* ml = (const float*)d_in[3];
  float* out = (float*)d_out;
  const size_t ybytes = (size_t)kB * kC * kL * sizeof(float);          // 64 MiB
  const size_t tabbytes = (size_t)kH * 2048 * 4 * sizeof(float2);      // 1 MiB
  if (ws_size >= ybytes + tabbytes) {
    float* ws = (float*)d_ws;
    float2* tab = (float2*)((char*)d_ws + ybytes);
    build_table<<<dim3(8, kH), dim3(256), 0, stream>>>(la, ld, tab);
    transpose_fwd<<<dim3(kL / 32, kC / 32, kB), dim3(256), 0, stream>>>(x, ws);
    fft_rows<<<dim3(kB * kC), dim3(NTH), 0, stream>>>(ws, tab);
    mix_out<<<dim3(kL / 32, kC / 32, kB), dim3(256), 0, stream>>>(ws, x, ml, out);
  } else {
    fftconv_fallback<<<dim3(kB * kC), dim3(NTH), 0, stream>>>(x, la, ld, ml, out);
  }
}

// Round 6
// 116.374 us; speedup vs baseline: 1.2002x; 1.2002x over previous
//
#include <hip/hip_runtime.h>
#include <math.h>

namespace {
constexpr int kB = 4;
constexpr int kL = 4096;
constexpr int kH = 16;
constexpr int kD = 64;
constexpr int kC = kH * kD;       // 1024 channels
constexpr int kM = 4096;          // complex FFT length (rfft of 8192 via packing)
constexpr int NTH = 256;
constexpr int kTabIters = 9;      // pointwise iterations 0..8

// ---------------- scalar complex helpers (aux kernels) ----------------
__device__ __forceinline__ float2 cmul(float2 a, float2 b) {
  return make_float2(a.x * b.x - a.y * b.y, a.x * b.y + a.y * b.x);
}
__device__ __forceinline__ float2 cadd(float2 a, float2 b) { return make_float2(a.x + b.x, a.y + b.y); }
__device__ __forceinline__ float2 csub(float2 a, float2 b) { return make_float2(a.x - b.x, a.y - b.y); }
__device__ __forceinline__ float2 cconj(float2 a) { return make_float2(a.x, -a.y); }
__device__ __forceinline__ float2 cmuli(float2 a) { return make_float2(-a.y, a.x); }  // i*a
__device__ __forceinline__ float2 cscale(float2 a, float s) { return make_float2(a.x * s, a.y * s); }

// ---------------- packed-FP32 complex helpers (fft_rows) ----------------
typedef float cplx __attribute__((ext_vector_type(2)));

__device__ __forceinline__ cplx pk_add(cplx a, cplx b) {
  cplx r;
  asm("v_pk_add_f32 %0, %1, %2" : "=v"(r) : "v"(a), "v"(b));
  return r;
}
__device__ __forceinline__ cplx pk_sub(cplx a, cplx b) {
  cplx r;
  asm("v_pk_add_f32 %0, %1, %2 neg_lo:[0,1] neg_hi:[0,1]" : "=v"(r) : "v"(a), "v"(b));
  return r;
}
// a + i*b = (a.x - b.y, a.y + b.x)
__device__ __forceinline__ cplx pk_addpi(cplx a, cplx b) {
  cplx r;
  asm("v_pk_add_f32 %0, %1, %2 op_sel:[0,1] op_sel_hi:[1,0] neg_lo:[0,1]" : "=v"(r) : "v"(a), "v"(b));
  return r;
}
// a - i*b = (a.x + b.y, a.y - b.x)
__device__ __forceinline__ cplx pk_addmi(cplx a, cplx b) {
  cplx r;
  asm("v_pk_add_f32 %0, %1, %2 op_sel:[0,1] op_sel_hi:[1,0] neg_hi:[0,1]" : "=v"(r) : "v"(a), "v"(b));
  return r;
}
// complex multiply: 2 VOP3P ops
__device__ __forceinline__ cplx pk_cmul(cplx a, cplx b) {
  cplx t, r;
  asm("v_pk_mul_f32 %0, %1, %2 op_sel:[0,0] op_sel_hi:[0,1]" : "=v"(t) : "v"(a), "v"(b));
  asm("v_pk_fma_f32 %0, %1, %2, %3 op_sel:[1,1,0] op_sel_hi:[1,0,1] neg_lo:[0,1,0]"
      : "=v"(r) : "v"(a), "v"(b), "v"(t));
  return r;
}

// base-4 digit reversal of a 12-bit index (fallback kernel only)
__device__ __forceinline__ unsigned dr4(unsigned p) {
  unsigned r = __brev(p) >> 20;
  return ((r & 0x555u) << 1) | ((r >> 1) & 0x555u);
}
// base-16 digit reversal of a 12-bit index (involution)
__device__ __forceinline__ unsigned dr16(unsigned p) {
  return ((p & 15u) << 8) | (p & 0xF0u) | (p >> 8);
}
// XOR LDS swizzle (cplx index space): phys = p ^ ((p>>4)&15).
// Every stage's 16-lane access is a permuted aligned 16-run -> conflict-free.
__device__ __forceinline__ int SW(int i) { return i ^ ((i >> 4) & 15); }
// after in-register DFT16, X[k] lives at register slot POS(k)
#define POS(k) ((((k) & 3) << 2) | ((k) >> 2))

// fallback-kernel padding
__device__ __forceinline__ int IDX(int i) { return i + (i >> 4); }
constexpr int kZPad = kM + (kM >> 4);

// depth-4 twiddle power tree: W1..W15 = w^1..w^15
#define TW_TREE(w)                                                            \
  cplx W1 = (w), W2 = pk_cmul(W1, W1), W4 = pk_cmul(W2, W2),                  \
       W8 = pk_cmul(W4, W4);                                                  \
  cplx W3 = pk_cmul(W2, W1), W5 = pk_cmul(W4, W1), W6 = pk_cmul(W4, W2),      \
       W7 = pk_cmul(W4, W3);                                                  \
  cplx W9 = pk_cmul(W8, W1), W10 = pk_cmul(W8, W2), W11 = pk_cmul(W8, W3),    \
       W12 = pk_cmul(W8, W4);                                                 \
  cplx W13 = pk_cmul(W8, W5), W14 = pk_cmul(W8, W6), W15 = pk_cmul(W8, W7);

#define TW_APPLY(r)                                                           \
  r[POS(1)] = pk_cmul(r[POS(1)], W1);   r[POS(2)] = pk_cmul(r[POS(2)], W2);   \
  r[POS(3)] = pk_cmul(r[POS(3)], W3);   r[POS(4)] = pk_cmul(r[POS(4)], W4);   \
  r[POS(5)] = pk_cmul(r[POS(5)], W5);   r[POS(6)] = pk_cmul(r[POS(6)], W6);   \
  r[POS(7)] = pk_cmul(r[POS(7)], W7);   r[POS(8)] = pk_cmul(r[POS(8)], W8);   \
  r[POS(9)] = pk_cmul(r[POS(9)], W9);   r[POS(10)] = pk_cmul(r[POS(10)], W10);\
  r[POS(11)] = pk_cmul(r[POS(11)], W11); r[POS(12)] = pk_cmul(r[POS(12)], W12);\
  r[POS(13)] = pk_cmul(r[POS(13)], W13); r[POS(14)] = pk_cmul(r[POS(14)], W14);\
  r[POS(15)] = pk_cmul(r[POS(15)], W15);

// shifted tree: B[k] = b0 * w^k, k = 0..15, depth ~4
#define TWS_TREE(b0, w)                                                       \
  cplx P2 = pk_cmul(w, w), P4 = pk_cmul(P2, P2), P8 = pk_cmul(P4, P4);        \
  cplx B0 = (b0), B1 = pk_cmul(b0, w), B2 = pk_cmul(B0, P2),                  \
       B3 = pk_cmul(B1, P2);                                                  \
  cplx B4 = pk_cmul(B0, P4), B5 = pk_cmul(B1, P4), B6 = pk_cmul(B2, P4),      \
       B7 = pk_cmul(B3, P4);                                                  \
  cplx B8 = pk_cmul(B0, P8), B9 = pk_cmul(B1, P8), B10 = pk_cmul(B2, P8),     \
       B11 = pk_cmul(B3, P8);                                                 \
  cplx B12 = pk_cmul(B4, P8), B13 = pk_cmul(B5, P8), B14 = pk_cmul(B6, P8),   \
       B15 = pk_cmul(B7, P8);

#define TWS_APPLY(r)                                                          \
  r[POS(0)] = pk_cmul(r[POS(0)], B0);   r[POS(1)] = pk_cmul(r[POS(1)], B1);   \
  r[POS(2)] = pk_cmul(r[POS(2)], B2);   r[POS(3)] = pk_cmul(r[POS(3)], B3);   \
  r[POS(4)] = pk_cmul(r[POS(4)], B4);   r[POS(5)] = pk_cmul(r[POS(5)], B5);   \
  r[POS(6)] = pk_cmul(r[POS(6)], B6);   r[POS(7)] = pk_cmul(r[POS(7)], B7);   \
  r[POS(8)] = pk_cmul(r[POS(8)], B8);   r[POS(9)] = pk_cmul(r[POS(9)], B9);   \
  r[POS(10)] = pk_cmul(r[POS(10)], B10); r[POS(11)] = pk_cmul(r[POS(11)], B11);\
  r[POS(12)] = pk_cmul(r[POS(12)], B12); r[POS(13)] = pk_cmul(r[POS(13)], B13);\
  r[POS(14)] = pk_cmul(r[POS(14)], B14); r[POS(15)] = pk_cmul(r[POS(15)], B15);

// filt[k] = amp * (1 + i k)^(-dec), with 1/M ifft scale folded into ampS
__device__ __forceinline__ float2 filt_val(float k, float ampS, float dec) {
  float mag = ampS * __expf(-0.5f * dec * log1pf(k * k));
  float ph = -dec * atanf(k);
  float s, c;
  __sincosf(ph, &s, &c);
  return make_float2(mag * c, mag * s);
}

// ---- fully-unrolled 16-point DFT in registers (packed-FP32) ----
// S = -1 forward, +1 inverse (unnormalized). HZ: inputs r[8..15] treated as 0.
// Output X[k] at slot POS(k).
template <int S, bool HZ>
__device__ __forceinline__ void fft16(cplx r[16]) {
  constexpr float C1 = 0.92387953251128674f;
  constexpr float S1 = 0.38268343236508978f;
  constexpr float R2 = 0.70710678118654752f;
  const float sg = (float)S;
  const cplx Wa = {C1, sg * S1};
  const cplx Wb = {R2, sg * R2};
  const cplx Wc = {S1, sg * C1};
  const cplx Wd = {-R2, sg * R2};
  const cplx We = {-C1, -sg * S1};
#pragma unroll
  for (int n2 = 0; n2 < 4; ++n2) {
    cplx t0, t1, t2, t3;
    if (HZ) {
      t0 = r[n2]; t1 = r[n2]; t2 = r[n2 + 4]; t3 = r[n2 + 4];
    } else {
      cplx a0 = r[n2], a1 = r[n2 + 4], a2 = r[n2 + 8], a3 = r[n2 + 12];
      t0 = pk_add(a0, a2); t1 = pk_sub(a0, a2); t2 = pk_add(a1, a3); t3 = pk_sub(a1, a3);
    }
    cplx u0 = pk_add(t0, t2);
    cplx u2 = pk_sub(t0, t2);
    cplx u1 = (S < 0) ? pk_addmi(t1, t3) : pk_addpi(t1, t3);
    cplx u3 = (S < 0) ? pk_addpi(t1, t3) : pk_addmi(t1, t3);
    if (n2 == 0) { r[0] = u0; r[4] = u1; r[8] = u2; r[12] = u3; }
    if (n2 == 1) { r[1] = u0; r[5] = pk_cmul(u1, Wa); r[9] = pk_cmul(u2, Wb); r[13] = pk_cmul(u3, Wc); }
    if (n2 == 2) {
      r[2] = u0; r[6] = pk_cmul(u1, Wb);
      cplx m;
      if (S < 0) { m.x = u2.y; m.y = -u2.x; } else { m.x = -u2.y; m.y = u2.x; }
      r[10] = m;
      r[14] = pk_cmul(u3, Wd);
    }
    if (n2 == 3) { r[3] = u0; r[7] = pk_cmul(u1, Wc); r[11] = pk_cmul(u2, Wd); r[15] = pk_cmul(u3, We); }
  }
#pragma unroll
  for (int s = 0; s < 4; ++s) {
    cplx b0 = r[4 * s], b1 = r[4 * s + 1], b2 = r[4 * s + 2], b3 = r[4 * s + 3];
    cplx t0 = pk_add(b0, b2), t1 = pk_sub(b0, b2), t2 = pk_add(b1, b3), t3 = pk_sub(b1, b3);
    r[4 * s] = pk_add(t0, t2);
    r[4 * s + 2] = pk_sub(t0, t2);
    r[4 * s + 1] = (S < 0) ? pk_addmi(t1, t3) : pk_addpi(t1, t3);
    r[4 * s + 3] = (S < 0) ? pk_addpi(t1, t3) : pk_addmi(t1, t3);
  }
}

// pointwise pair map (verified algebra; identities valid for any k in 1..4095),
// used only by build_table
__device__ __forceinline__ void pw_pair(float2 Zk, float2 Zmk, int k, float ampS, float dec,
                                        float2* Wk, float2* Wmk) {
  float2 A = cscale(cadd(Zk, cconj(Zmk)), 0.5f);
  float2 Bv = cscale(csub(Zk, cconj(Zmk)), 0.5f);
  float sn, cs;
  __sincosf(-3.14159265358979323846f * (float)k / (float)kM, &sn, &cs);
  float2 tw = make_float2(cs, sn);
  float2 P = cmuli(cmul(tw, Bv));
  float2 Xk = csub(A, P);
  float2 Xmk = cconj(cadd(A, P));
  float2 Yk = cmul(Xk, filt_val((float)k, ampS, dec));
  float2 Ymk = cmul(Xmk, filt_val((float)(kM - k), ampS, dec));
  float2 Ev = cscale(cadd(Yk, cconj(Ymk)), 0.5f);
  float2 Ov = cscale(cmul(cconj(tw), csub(Yk, cconj(Ymk))), 0.5f);
  float2 iO = cmuli(Ov);
  *Wk = cadd(Ev, iO);
  *Wmk = cconj(csub(Ev, iO));
}
}  // namespace

// ---------- pass 0: coefficient table keyed by (h, iter, lane) ----------
// iter i, lane t owns position p = i*256 + t (bin k = dr16(p)); coalesced in kernel.
__global__ __launch_bounds__(256) void build_table(const float* __restrict__ la,
                                                   const float* __restrict__ ld,
                                                   float2* __restrict__ tab) {
  const int i = blockIdx.x;   // 0..8
  const int h = blockIdx.y;
  const int t = threadIdx.x;  // 0..255
  float av = la[h], dv = ld[h];
  float amp = (av > 20.f) ? av : log1pf(__expf(av));
  float dec = ((dv > 20.f) ? dv : log1pf(__expf(dv))) + 1e-4f;
  float ampS = amp * (1.0f / (float)kM);
  float2 e0 = make_float2(0.f, 0.f), e1 = e0, e2 = e0, e3 = e0;
  const int c = t & 15;
  if (i == 0 && t == 0) {
    float F0 = filt_val(0.f, ampS, dec).x;
    float FM = filt_val((float)kM, ampS, dec).x;
    e0 = make_float2(0.5f * (F0 + FM), 0.5f * (F0 - FM));
    e1 = make_float2(0.5f * (F0 - FM), 0.5f * (F0 + FM));
  } else if (i == 0 && t == 8) {
    e0 = cconj(filt_val((float)(kM / 2), ampS, dec));  // bin 2048 single coeff
  } else if ((i >= 1 && i <= 7) || c < 8) {
    int p = (i << 8) + t;
    int k = (int)dr16((unsigned)p);
    float2 a, b, g, d;
    pw_pair(make_float2(1.f, 0.f), make_float2(0.f, 0.f), k, ampS, dec, &a, &g);
    pw_pair(make_float2(0.f, 0.f), make_float2(1.f, 0.f), k, ampS, dec, &b, &d);
    e0 = a; e1 = b; e2 = g; e3 = d;
  }
  float2* e = tab + ((size_t)(h * kTabIters + i) * 256 + t) * 4;
  e[0] = e0; e[1] = e1; e[2] = e2; e[3] = e3;
}

// ---------- pass 1: transpose x (B, L, C) -> ws (B, C, L), coalesced ----------
__global__ __launch_bounds__(256) void transpose_fwd(const float* __restrict__ in,
                                                     float* __restrict__ outp) {
  __shared__ float T[32][33];
  const int b = blockIdx.z;
  const int r0 = blockIdx.x * 32;  // l
  const int c0 = blockIdx.y * 32;  // c
  const float* ib = in + (size_t)b * kL * kC;
  float* ob = outp + (size_t)b * kC * kL;
  const int tx = threadIdx.x & 31, ty = threadIdx.x >> 5;
  for (int i = 0; i < 32; i += 8)
    T[ty + i][tx] = ib[(size_t)(r0 + ty + i) * kC + c0 + tx];
  __syncthreads();
  for (int i = 0; i < 32; i += 8)
    ob[(size_t)(c0 + ty + i) * kL + r0 + tx] = T[tx][ty + i];
}

// ---------- pass 2: per-row FFT conv (16^3 register radix-16, packed math) ----------
__global__ __launch_bounds__(NTH) void fft_rows(float* __restrict__ ws,
                                                const float2* __restrict__ tab) {
  __shared__ cplx Z[kM];  // exactly 32 KB
  const int row = blockIdx.x;  // b*1024 + c
  const int h = (row >> 6) & (kH - 1);
  const int t = threadIdx.x;
  cplx* xrow = (cplx*)(ws + (size_t)row * kL);  // 2048 cplx

  cplx r[16];
  const int swt = t ^ ((t >> 4) & 15);

  // ---- F1: global load (coalesced), DFT16 over n1, twiddle W4096^{t*k1} ----
#pragma unroll
  for (int j = 0; j < 8; ++j) r[j] = xrow[t + 256 * j];
  fft16<-1, true>(r);
  {
    float sn, cs;
    __sincosf(-6.283185307179586f * (float)t / 4096.f, &sn, &cs);
    cplx w = {cs, sn};
    TW_TREE(w);
    TW_APPLY(r);
    cplx* Zb = &Z[swt];
#pragma unroll
    for (int k1 = 0; k1 < 16; ++k1) Zb[k1 << 8] = r[POS(k1)];
  }
  __syncthreads();

  // ---- F2: DFT16 over m1 (stride 16), twiddle W256^{m2*j1} ----
  {
    const int g = t >> 4, m2 = t & 15;
    const int base = g << 8;
#pragma unroll
    for (int m1 = 0; m1 < 16; ++m1) r[m1] = Z[base + (m1 << 4) + (m2 ^ m1)];
    fft16<-1, false>(r);
    float sn, cs;
    __sincosf(-6.283185307179586f * (float)m2 / 256.f, &sn, &cs);
    cplx w = {cs, sn};
    TW_TREE(w);
    TW_APPLY(r);
#pragma unroll
    for (int j1 = 0; j1 < 16; ++j1) Z[base + (j1 << 4) + (m2 ^ j1)] = r[POS(j1)];
  }
  __syncthreads();

  // ---- F3: DFT16 over m2 (contiguous permuted 16), no twiddle ----
  {
    const int g = t >> 4, j1 = t & 15;
    const int base = (g << 8) + (j1 << 4);
#pragma unroll
    for (int m2 = 0; m2 < 16; ++m2) r[m2] = Z[base + (m2 ^ j1)];
    fft16<-1, false>(r);
#pragma unroll
    for (int j2 = 0; j2 < 16; ++j2) Z[base + (j2 ^ j1)] = r[POS(j2)];
  }
  __syncthreads();

  // ---- pointwise: position-indexed pairs, conflict-free & coalesced table ----
  // position p holds bin dr16(p); pair partner of p (i>=1): p2 = (16-i)<<8 | (255-t)
  {
    const int c = t & 15;
    const float4* tpz = (const float4*)(tab + (size_t)h * kTabIters * 256 * 4);
#pragma unroll
    for (int i = 0; i <= 8; ++i) {
      const float4* tp = tpz + ((i << 8) + t) * 2;
      float4 q0 = tp[0], q1 = tp[1];
      if (i == 0 && t == 0) {
        cplx Z0 = Z[0];
        cplx o; o.x = q0.x * Z0.x + q0.y * Z0.y; o.y = q0.z * Z0.x + q0.w * Z0.y;
        Z[0] = o;
      } else if (i == 0 && t == 8) {
        cplx f; f.x = q0.x; f.y = q0.y;
        Z[8] = pk_cmul(f, Z[8]);  // SW(8)=8, bin 2048
      } else if ((i >= 1 && i <= 7) || c < 8) {
        int p = (i << 8) + t;
        int p2 = (i == 0) ? ((t < 16) ? (16 - t) : (271 - t))
                          : (((16 - i) << 8) + (255 - t));
        int sp = SW(p), sp2 = SW(p2);
        cplx Zk = Z[sp], Zmk = Z[sp2];
        cplx e0 = {q0.x, q0.y}, e1 = {q0.z, q0.w};
        cplx e2 = {q1.x, q1.y}, e3 = {q1.z, q1.w};
        cplx cZk = {Zk.x, -Zk.y}, cZmk = {Zmk.x, -Zmk.y};
        Z[sp] = pk_add(pk_cmul(e0, Zk), pk_cmul(e1, cZmk));
        Z[sp2] = pk_add(pk_cmul(e2, cZk), pk_cmul(e3, Zmk));
      }
    }
  }
  __syncthreads();

  // ---- I1: IDFT16 over j2 (contiguous permuted 16), twiddle e^{+2pi i j1*m2/256} ----
  {
    const int k1 = t >> 4, j1 = t & 15;
    const int base = (k1 << 8) + (j1 << 4);
#pragma unroll
    for (int j2 = 0; j2 < 16; ++j2) r[j2] = Z[base + (j2 ^ j1)];
    fft16<1, false>(r);
    float sn, cs;
    __sincosf(6.283185307179586f * (float)j1 / 256.f, &sn, &cs);
    cplx w = {cs, sn};
    TW_TREE(w);
    TW_APPLY(r);
#pragma unroll
    for (int m2 = 0; m2 < 16; ++m2) Z[base + (m2 ^ j1)] = r[POS(m2)];
  }
  __syncthreads();

  // ---- I2: IDFT16 over j1 (stride 16), twiddle e^{+2pi i k1*(m1*16+m2)/4096} ----
  {
    const int k1 = t >> 4, m2 = t & 15;
#pragma unroll
    for (int j1 = 0; j1 < 16; ++j1) r[j1] = Z[(k1 << 8) + (j1 << 4) + (m2 ^ j1)];
    fft16<1, false>(r);
    float sn, cs;
    __sincosf(6.283185307179586f * (float)(k1 * m2) / 4096.f, &sn, &cs);
    cplx b0 = {cs, sn};
    __sincosf(6.283185307179586f * (float)k1 / 256.f, &sn, &cs);
    cplx w = {cs, sn};
    TWS_TREE(b0, w);
    TWS_APPLY(r);
#pragma unroll
    for (int m1 = 0; m1 < 16; ++m1) Z[(k1 << 8) + (m1 << 4) + (m2 ^ m1)] = r[POS(m1)];
  }
  __syncthreads();

  // ---- I3: IDFT16 over k1 (stride 256), direct coalesced global store ----
  {
    cplx* Zb = &Z[swt];
#pragma unroll
    for (int k1 = 0; k1 < 16; ++k1) r[k1] = Zb[k1 << 8];
    fft16<1, false>(r);
#pragma unroll
    for (int n1 = 0; n1 < 8; ++n1) xrow[(n1 << 8) + t] = r[POS(n1)];
  }
}

// ---------- pass 3: transpose back ws (B, C, L) -> out (B, L, C) + mix ----------
__global__ __launch_bounds__(256) void mix_out(const float* __restrict__ yT,
                                               const float* __restrict__ x,
                                               const float* __restrict__ mix_logit,
                                               float* __restrict__ outp) {
  __shared__ float T[32][33];
  const int b = blockIdx.z;
  const int r0 = blockIdx.x * 32;  // l
  const int c0 = blockIdx.y * 32;  // c
  const int h = c0 >> 6;
  const float ml = mix_logit[h];
  const float mix = 1.0f / (1.0f + __expf(-ml));
  const float omix = 1.0f - mix;
  const float* yb = yT + (size_t)b * kC * kL;
  const float* xb = x + (size_t)b * kL * kC;
  float* ob = outp + (size_t)b * kL * kC;
  const int tx = threadIdx.x & 31, ty = threadIdx.x >> 5;
  for (int i = 0; i < 32; i += 8)
    T[ty + i][tx] = yb[(size_t)(c0 + ty + i) * kL + r0 + tx];
  __syncthreads();
  for (int i = 0; i < 32; i += 8) {
    size_t idx = (size_t)(r0 + ty + i) * kC + c0 + tx;
    ob[idx] = mix * T[tx][ty + i] + omix * xb[idx];
  }
}

// ---------- fallback (round-1 single kernel) if ws is too small ----------
__global__ __launch_bounds__(NTH) void fftconv_fallback(
    const float* __restrict__ x, const float* __restrict__ log_amp,
    const float* __restrict__ log_decay, const float* __restrict__ mix_logit,
    float* __restrict__ out) {
  __shared__ float2 Z[kZPad];
  const int row = blockIdx.x;
  const int d = row & (kD - 1);
  const int h = (row >> 6) & (kH - 1);
  const int b = row >> 10;
  const int t = threadIdx.x;
  const size_t rowoff = (size_t)b * kL * kC + (size_t)h * kD + (size_t)d;
  const float* xrow = x + rowoff;
  float* orow = out + rowoff;

  const float av = log_amp[h];
  const float dv = log_decay[h];
  const float amp = (av > 20.f) ? av : log1pf(__expf(av));
  const float dec = ((dv > 20.f) ? dv : log1pf(__expf(dv))) + 1e-4f;
  const float ampS = amp * (1.0f / (float)kM);
  const float ml = mix_logit[h];
  const float mix = 1.0f / (1.0f + __expf(-ml));
  const float omix = 1.0f - mix;

  for (int i = 0; i < kM / NTH; ++i) {
    int n = t + i * NTH;
    float2 z;
    if (n < kL / 2) {
      z.x = xrow[(size_t)(2 * n) * kC];
      z.y = xrow[(size_t)(2 * n + 1) * kC];
    } else {
      z = make_float2(0.f, 0.f);
    }
    Z[IDX(n)] = z;
  }
  __syncthreads();

  for (int Ls = kM; Ls >= 4; Ls >>= 2) {
    const int q = Ls >> 2;
    const float wstep = -6.283185307179586f / (float)Ls;
    for (int i = 0; i < kM / 4 / NTH; ++i) {
      int bt = t + i * NTH;
      int jj = bt & (q - 1);
      int base = ((bt - jj) << 2) + jj;
      float2 a = Z[IDX(base)], bb = Z[IDX(base + q)];
      float2 c = Z[IDX(base + 2 * q)], dd = Z[IDX(base + 3 * q)];
      float2 t0 = cadd(a, c), t1 = csub(a, c), t2 = cadd(bb, dd), t3 = csub(bb, dd);
      float2 u0 = cadd(t0, t2), u2 = csub(t0, t2);
      float2 it3 = cmuli(t3);
      float2 u1 = csub(t1, it3), u3 = cadd(t1, it3);
      float sn, cs;
      __sincosf(wstep * (float)jj, &sn, &cs);
      float2 w1 = make_float2(cs, sn);
      float2 w2 = cmul(w1, w1);
      float2 w3 = cmul(w2, w1);
      Z[IDX(base)] = u0;
      Z[IDX(base + q)] = cmul(u1, w1);
      Z[IDX(base + 2 * q)] = cmul(u2, w2);
      Z[IDX(base + 3 * q)] = cmul(u3, w3);
    }
    __syncthreads();
  }

  for (int i = 0; i <= kM / 2 / NTH; ++i) {
    int k = t + i * NTH;
    if (k > kM / 2) continue;
    if (k == 0) {
      float2 Z0 = Z[IDX(0)];
      float X0 = Z0.x + Z0.y;
      float XM = Z0.x - Z0.y;
      float2 f0 = filt_val(0.f, ampS, dec);
      float2 fM = filt_val((float)kM, ampS, dec);
      float Y0 = X0 * f0.x;
      float YM = XM * fM.x;
      Z[IDX(0)] = make_float2(0.5f * (Y0 + YM), 0.5f * (Y0 - YM));
    } else if (k == kM / 2) {
      unsigned p = dr4(kM / 2);
      float2 Zk = Z[IDX(p)];
      float2 f = filt_val((float)(kM / 2), ampS, dec);
      float2 Y = cmul(cconj(Zk), f);
      Z[IDX(p)] = cconj(Y);
    } else {
      unsigned pk = dr4((unsigned)k), pmk = dr4((unsigned)(kM - k));
      float2 Zk = Z[IDX(pk)], Zmk = Z[IDX(pmk)];
      float2 A = cscale(cadd(Zk, cconj(Zmk)), 0.5f);
      float2 Bv = cscale(csub(Zk, cconj(Zmk)), 0.5f);
      float sn, cs;
      __sincosf(-3.14159265358979323846f * (float)k / (float)kM, &sn, &cs);
      float2 tw = make_float2(cs, sn);
      float2 P = cmuli(cmul(tw, Bv));
      float2 Xk = csub(A, P);
      float2 Xmk = cconj(cadd(A, P));
      float2 Yk = cmul(Xk, filt_val((float)k, ampS, dec));
      float2 Ymk = cmul(Xmk, filt_val((float)(kM - k), ampS, dec));
      float2 Ev = cscale(cadd(Yk, cconj(Ymk)), 0.5f);
      float2 Ov = cscale(cmul(cconj(tw), csub(Yk, cconj(Ymk))), 0.5f);
      float2 iO = cmuli(Ov);
      Z[IDX(pk)] = cadd(Ev, iO);
      Z[IDX(pmk)] = cconj(csub(Ev, iO));
    }
  }
  __syncthreads();

  for (int Ls = 4; Ls <= kM; Ls <<= 2) {
    const int q = Ls >> 2;
    const float wstep = 6.283185307179586f / (float)Ls;
    for (int i = 0; i < kM / 4 / NTH; ++i) {
      int bt = t + i * NTH;
      int jj = bt & (q - 1);
      int base = ((bt - jj) << 2) + jj;
      float sn, cs;
      __sincosf(wstep * (float)jj, &sn, &cs);
      float2 w1 = make_float2(cs, sn);
      float2 w2 = cmul(w1, w1);
      float2 w3 = cmul(w2, w1);
      float2 a = Z[IDX(base)];
      float2 bb = cmul(Z[IDX(base + q)], w1);
      float2 c = cmul(Z[IDX(base + 2 * q)], w2);
      float2 dd = cmul(Z[IDX(base + 3 * q)], w3);
      float2 s0 = cadd(a, c), s1 = csub(a, c), s2 = cadd(bb, dd), s3 = csub(bb, dd);
      float2 is3 = cmuli(s3);
      Z[IDX(base)] = cadd(s0, s2);
      Z[IDX(base + 2 * q)] = csub(s0, s2);
      Z[IDX(base + q)] = cadd(s1, is3);
      Z[IDX(base + 3 * q)] = csub(s1, is3);
    }
    __syncthreads();
  }

  for (int i = 0; i < kL / 2 / NTH; ++i) {
    int n = t + i * NTH;
    float2 w = Z[IDX(n)];
    size_t i0 = (size_t)(2 * n) * kC;
    float x0 = xrow[i0];
    float x1 = xrow[i0 + kC];
    orow[i0] = mix * w.x + omix * x0;
    orow[i0 + kC] = mix * w.y + omix * x1;
  }
}

extern "C" void kernel_launch(void* const* d_in, const int* in_sizes, int n_in,
                              void* d_out, int out_size, void* d_ws, size_t ws_size,
                              hipStream_t stream) {
  const float* x = (const float*)d_in[0];
  const float* la = (const float*)d_in[1];
  const float* ld = (const float*)d_in[2];
  const float* ml = (const float*)d_in[3];
  float* out = (float*)d_out;
  const size_t ybytes = (size_t)kB * kC * kL * sizeof(float);                    // 64 MiB
  const size_t tabbytes = (size_t)kH * kTabIters * 256 * 4 * sizeof(float2);     // ~1.1 MiB
  if (ws_size >= ybytes + tabbytes) {
    float* ws = (float*)d_ws;
    float2* tab = (float2*)((char*)d_ws + ybytes);
    build_table<<<dim3(kTabIters, kH), dim3(256), 0, stream>>>(la, ld, tab);
    transpose_fwd<<<dim3(kL / 32, kC / 32, kB), dim3(256), 0, stream>>>(x, ws);
    fft_rows<<<dim3(kB * kC), dim3(NTH), 0, stream>>>(ws, tab);
    mix_out<<<dim3(kL / 32, kC / 32, kB), dim3(256), 0, stream>>>(ws, x, ml, out);
  } else {
    fftconv_fallback<<<dim3(kB * kC), dim3(NTH), 0, stream>>>(x, la, ld, ml, out);
  }
}

// Round 7
// 108.626 us; speedup vs baseline: 1.2858x; 1.0713x over previous
//
#include <hip/hip_runtime.h>
#include <math.h>

namespace {
constexpr int kB = 4;
constexpr int kL = 4096;
constexpr int kH = 16;
constexpr int kD = 64;
constexpr int kC = kH * kD;       // 1024 channels
constexpr int kM = 4096;          // complex FFT length (rfft of 8192 via packing)
constexpr int kN2 = kL / 2;       // 2048 packed complex samples per row
constexpr int NTH = 256;
constexpr int kTabIters = 9;      // pointwise iterations 0..8

// ---------------- scalar complex helpers (aux kernels) ----------------
__device__ __forceinline__ float2 cmul(float2 a, float2 b) {
  return make_float2(a.x * b.x - a.y * b.y, a.x * b.y + a.y * b.x);
}
__device__ __forceinline__ float2 cadd(float2 a, float2 b) { return make_float2(a.x + b.x, a.y + b.y); }
__device__ __forceinline__ float2 csub(float2 a, float2 b) { return make_float2(a.x - b.x, a.y - b.y); }
__device__ __forceinline__ float2 cconj(float2 a) { return make_float2(a.x, -a.y); }
__device__ __forceinline__ float2 cmuli(float2 a) { return make_float2(-a.y, a.x); }  // i*a
__device__ __forceinline__ float2 cscale(float2 a, float s) { return make_float2(a.x * s, a.y * s); }

// ---------------- packed-FP32 complex helpers (fft_rows) ----------------
typedef float cplx __attribute__((ext_vector_type(2)));

__device__ __forceinline__ cplx pk_add(cplx a, cplx b) {
  cplx r;
  asm("v_pk_add_f32 %0, %1, %2" : "=v"(r) : "v"(a), "v"(b));
  return r;
}
__device__ __forceinline__ cplx pk_sub(cplx a, cplx b) {
  cplx r;
  asm("v_pk_add_f32 %0, %1, %2 neg_lo:[0,1] neg_hi:[0,1]" : "=v"(r) : "v"(a), "v"(b));
  return r;
}
// a + i*b = (a.x - b.y, a.y + b.x)
__device__ __forceinline__ cplx pk_addpi(cplx a, cplx b) {
  cplx r;
  asm("v_pk_add_f32 %0, %1, %2 op_sel:[0,1] op_sel_hi:[1,0] neg_lo:[0,1]" : "=v"(r) : "v"(a), "v"(b));
  return r;
}
// a - i*b = (a.x + b.y, a.y - b.x)
__device__ __forceinline__ cplx pk_addmi(cplx a, cplx b) {
  cplx r;
  asm("v_pk_add_f32 %0, %1, %2 op_sel:[0,1] op_sel_hi:[1,0] neg_hi:[0,1]" : "=v"(r) : "v"(a), "v"(b));
  return r;
}
// complex multiply: 2 VOP3P ops
__device__ __forceinline__ cplx pk_cmul(cplx a, cplx b) {
  cplx t, r;
  asm("v_pk_mul_f32 %0, %1, %2 op_sel:[0,0] op_sel_hi:[0,1]" : "=v"(t) : "v"(a), "v"(b));
  asm("v_pk_fma_f32 %0, %1, %2, %3 op_sel:[1,1,0] op_sel_hi:[1,0,1] neg_lo:[0,1,0]"
      : "=v"(r) : "v"(a), "v"(b), "v"(t));
  return r;
}

// bf16x2 pack (RNE) / unpack
__device__ __forceinline__ unsigned pkbf(float lo, float hi) {
  unsigned r;
  asm("v_cvt_pk_bf16_f32 %0, %1, %2" : "=v"(r) : "v"(lo), "v"(hi));
  return r;
}
__device__ __forceinline__ cplx unpk(unsigned d) {
  cplx r;
  r.x = __uint_as_float(d << 16);
  r.y = __uint_as_float(d & 0xffff0000u);
  return r;
}

// base-4 digit reversal of a 12-bit index (fallback kernel only)
__device__ __forceinline__ unsigned dr4(unsigned p) {
  unsigned r = __brev(p) >> 20;
  return ((r & 0x555u) << 1) | ((r >> 1) & 0x555u);
}
// base-16 digit reversal of a 12-bit index (involution)
__device__ __forceinline__ unsigned dr16(unsigned p) {
  return ((p & 15u) << 8) | (p & 0xF0u) | (p >> 8);
}
// XOR LDS swizzle (cplx index space): phys = p ^ ((p>>4)&15)
__device__ __forceinline__ int SW(int i) { return i ^ ((i >> 4) & 15); }
// after in-register DFT16, X[k] lives at register slot POS(k)
#define POS(k) ((((k) & 3) << 2) | ((k) >> 2))

// fallback-kernel padding
__device__ __forceinline__ int IDX(int i) { return i + (i >> 4); }
constexpr int kZPad = kM + (kM >> 4);

// filt[k] = amp * (1 + i k)^(-dec), with 1/M ifft scale folded into ampS
__device__ __forceinline__ float2 filt_val(float k, float ampS, float dec) {
  float mag = ampS * __expf(-0.5f * dec * log1pf(k * k));
  float ph = -dec * atanf(k);
  float s, c;
  __sincosf(ph, &s, &c);
  return make_float2(mag * c, mag * s);
}

// ---- fully-unrolled 16-point DFT in registers (packed-FP32) ----
template <int S, bool HZ>
__device__ __forceinline__ void fft16(cplx r[16]) {
  constexpr float C1 = 0.92387953251128674f;
  constexpr float S1 = 0.38268343236508978f;
  constexpr float R2 = 0.70710678118654752f;
  const float sg = (float)S;
  const cplx Wa = {C1, sg * S1};
  const cplx Wb = {R2, sg * R2};
  const cplx Wc = {S1, sg * C1};
  const cplx Wd = {-R2, sg * R2};
  const cplx We = {-C1, -sg * S1};
#pragma unroll
  for (int n2 = 0; n2 < 4; ++n2) {
    cplx t0, t1, t2, t3;
    if (HZ) {
      t0 = r[n2]; t1 = r[n2]; t2 = r[n2 + 4]; t3 = r[n2 + 4];
    } else {
      cplx a0 = r[n2], a1 = r[n2 + 4], a2 = r[n2 + 8], a3 = r[n2 + 12];
      t0 = pk_add(a0, a2); t1 = pk_sub(a0, a2); t2 = pk_add(a1, a3); t3 = pk_sub(a1, a3);
    }
    cplx u0 = pk_add(t0, t2);
    cplx u2 = pk_sub(t0, t2);
    cplx u1 = (S < 0) ? pk_addmi(t1, t3) : pk_addpi(t1, t3);
    cplx u3 = (S < 0) ? pk_addpi(t1, t3) : pk_addmi(t1, t3);
    if (n2 == 0) { r[0] = u0; r[4] = u1; r[8] = u2; r[12] = u3; }
    if (n2 == 1) { r[1] = u0; r[5] = pk_cmul(u1, Wa); r[9] = pk_cmul(u2, Wb); r[13] = pk_cmul(u3, Wc); }
    if (n2 == 2) {
      r[2] = u0; r[6] = pk_cmul(u1, Wb);
      cplx m;
      if (S < 0) { m.x = u2.y; m.y = -u2.x; } else { m.x = -u2.y; m.y = u2.x; }
      r[10] = m;
      r[14] = pk_cmul(u3, Wd);
    }
    if (n2 == 3) { r[3] = u0; r[7] = pk_cmul(u1, Wc); r[11] = pk_cmul(u2, Wd); r[15] = pk_cmul(u3, We); }
  }
#pragma unroll
  for (int s = 0; s < 4; ++s) {
    cplx b0 = r[4 * s], b1 = r[4 * s + 1], b2 = r[4 * s + 2], b3 = r[4 * s + 3];
    cplx t0 = pk_add(b0, b2), t1 = pk_sub(b0, b2), t2 = pk_add(b1, b3), t3 = pk_sub(b1, b3);
    r[4 * s] = pk_add(t0, t2);
    r[4 * s + 2] = pk_sub(t0, t2);
    r[4 * s + 1] = (S < 0) ? pk_addmi(t1, t3) : pk_addpi(t1, t3);
    r[4 * s + 3] = (S < 0) ? pk_addpi(t1, t3) : pk_addmi(t1, t3);
  }
}

// pointwise pair map (verified algebra), used only by build_table
__device__ __forceinline__ void pw_pair(float2 Zk, float2 Zmk, int k, float ampS, float dec,
                                        float2* Wk, float2* Wmk) {
  float2 A = cscale(cadd(Zk, cconj(Zmk)), 0.5f);
  float2 Bv = cscale(csub(Zk, cconj(Zmk)), 0.5f);
  float sn, cs;
  __sincosf(-3.14159265358979323846f * (float)k / (float)kM, &sn, &cs);
  float2 tw = make_float2(cs, sn);
  float2 P = cmuli(cmul(tw, Bv));
  float2 Xk = csub(A, P);
  float2 Xmk = cconj(cadd(A, P));
  float2 Yk = cmul(Xk, filt_val((float)k, ampS, dec));
  float2 Ymk = cmul(Xmk, filt_val((float)(kM - k), ampS, dec));
  float2 Ev = cscale(cadd(Yk, cconj(Ymk)), 0.5f);
  float2 Ov = cscale(cmul(cconj(tw), csub(Yk, cconj(Ymk))), 0.5f);
  float2 iO = cmuli(Ov);
  *Wk = cadd(Ev, iO);
  *Wmk = cconj(csub(Ev, iO));
}
}  // namespace

// ---------- pass 0a: coefficient table keyed by (h, iter, lane) ----------
__global__ __launch_bounds__(256) void build_table(const float* __restrict__ la,
                                                   const float* __restrict__ ld,
                                                   float2* __restrict__ tab) {
  const int i = blockIdx.x;   // 0..8
  const int h = blockIdx.y;
  const int t = threadIdx.x;  // 0..255
  float av = la[h], dv = ld[h];
  float amp = (av > 20.f) ? av : log1pf(__expf(av));
  float dec = ((dv > 20.f) ? dv : log1pf(__expf(dv))) + 1e-4f;
  float ampS = amp * (1.0f / (float)kM);
  float2 e0 = make_float2(0.f, 0.f), e1 = e0, e2 = e0, e3 = e0;
  const int c = t & 15;
  if (i == 0 && t == 0) {
    float F0 = filt_val(0.f, ampS, dec).x;
    float FM = filt_val((float)kM, ampS, dec).x;
    e0 = make_float2(0.5f * (F0 + FM), 0.5f * (F0 - FM));
    e1 = make_float2(0.5f * (F0 - FM), 0.5f * (F0 + FM));
  } else if (i == 0 && t == 8) {
    e0 = cconj(filt_val((float)(kM / 2), ampS, dec));  // bin 2048 single coeff
  } else if ((i >= 1 && i <= 7) || c < 8) {
    int p = (i << 8) + t;
    int k = (int)dr16((unsigned)p);
    float2 a, b, g, d;
    pw_pair(make_float2(1.f, 0.f), make_float2(0.f, 0.f), k, ampS, dec, &a, &g);
    pw_pair(make_float2(0.f, 0.f), make_float2(1.f, 0.f), k, ampS, dec, &b, &d);
    e0 = a; e1 = b; e2 = g; e3 = d;
  }
  float2* e = tab + ((size_t)(h * kTabIters + i) * 256 + t) * 4;
  e[0] = e0; e[1] = e1; e[2] = e2; e[3] = e3;
}

// ---------- pass 0b: twiddle tables (precise sincosf), L2-resident ----------
// layout (float2 units): twF1[15][256] | twI2[16][256] | twF2[15][16] | twI1[15][16]
__global__ __launch_bounds__(256) void build_tw(float2* __restrict__ tw) {
  const int j = blockIdx.x;   // 0..15
  const int t = threadIdx.x;  // 0..255
  const float TP = 6.28318530717958647692f;
  float s, c;
  if (j < 15) {
    sincosf(-TP * (float)((j + 1) * t) * (1.f / 4096.f), &s, &c);
    tw[j * 256 + t] = make_float2(c, s);
  }
  {
    int k1 = t >> 4, m2 = t & 15;
    sincosf(TP * (float)(k1 * (m2 + 16 * j)) * (1.f / 4096.f), &s, &c);
    tw[15 * 256 + j * 256 + t] = make_float2(c, s);
  }
  if (j < 15 && t < 16) {
    sincosf(-TP * (float)((j + 1) * t) * (1.f / 256.f), &s, &c);
    tw[31 * 256 + j * 16 + t] = make_float2(c, s);        // twF2 (forward)
    tw[31 * 256 + 240 + j * 16 + t] = make_float2(c, -s); // twI1 (conj)
  }
}

// ---------- pass 1: transpose + pack x (B,L,C) -> z bf16x2 (B,C,L/2) ----------
__global__ __launch_bounds__(256) void transpose_fwd(const float* __restrict__ in,
                                                     unsigned* __restrict__ zout) {
  __shared__ float T[64][33];
  const int b = blockIdx.z;
  const int l0 = blockIdx.x * 64;
  const int c0 = blockIdx.y * 32;
  const float* ib = in + (size_t)b * kL * kC;
  unsigned* ob = zout + (size_t)b * kC * kN2;
  const int tx = threadIdx.x & 31, ty = threadIdx.x >> 5;
#pragma unroll
  for (int i = 0; i < 64; i += 8)
    T[ty + i][tx] = ib[(size_t)(l0 + ty + i) * kC + c0 + tx];
  __syncthreads();
  const int n0 = l0 >> 1;
#pragma unroll
  for (int i = 0; i < 32; i += 8) {
    int c = ty + i;
    ob[(size_t)(c0 + c) * kN2 + n0 + tx] = pkbf(T[2 * tx][c], T[2 * tx + 1][c]);
  }
}

// ---------- pass 2: per-row FFT conv (16^3 register radix-16, packed math) ----------
__global__ __launch_bounds__(NTH) void fft_rows(unsigned* __restrict__ zio,
                                                const float2* __restrict__ tab,
                                                const cplx* __restrict__ twF1,
                                                const cplx* __restrict__ twI2,
                                                const cplx* __restrict__ twF2s,
                                                const cplx* __restrict__ twI1s) {
  __shared__ cplx Z[kM];  // 32 KB
  const int row = blockIdx.x;  // b*1024 + c
  const int h = (row >> 6) & (kH - 1);
  const int t = threadIdx.x;
  unsigned* zrow = zio + (size_t)row * kN2;

  cplx r[16], tw[15];
  const int swt = t ^ ((t >> 4) & 15);

  // ---- F1: global load (bf16x2 dwords), DFT16 over n1, table twiddle ----
  {
    unsigned din[8];
#pragma unroll
    for (int j = 0; j < 8; ++j) din[j] = zrow[t + (j << 8)];
#pragma unroll
    for (int p = 1; p < 16; ++p) tw[p - 1] = twF1[((p - 1) << 8) + t];
#pragma unroll
    for (int j = 0; j < 8; ++j) r[j] = unpk(din[j]);
    fft16<-1, true>(r);
#pragma unroll
    for (int p = 1; p < 16; ++p) r[POS(p)] = pk_cmul(r[POS(p)], tw[p - 1]);
    cplx* Zb = &Z[swt];
#pragma unroll
    for (int k1 = 0; k1 < 16; ++k1) Zb[k1 << 8] = r[POS(k1)];
  }
  __syncthreads();

  // ---- F2: DFT16 over m1 (stride 16), table twiddle W256^{m2*j1} ----
  {
    const int g = t >> 4, m2 = t & 15;
    const int base = g << 8;
#pragma unroll
    for (int p = 1; p < 16; ++p) tw[p - 1] = twF2s[((p - 1) << 4) + m2];
#pragma unroll
    for (int m1 = 0; m1 < 16; ++m1) r[m1] = Z[base + (m1 << 4) + (m2 ^ m1)];
    fft16<-1, false>(r);
#pragma unroll
    for (int p = 1; p < 16; ++p) r[POS(p)] = pk_cmul(r[POS(p)], tw[p - 1]);
#pragma unroll
    for (int j1 = 0; j1 < 16; ++j1) Z[base + (j1 << 4) + (m2 ^ j1)] = r[POS(j1)];
  }
  __syncthreads();

  // ---- F3: DFT16 over m2 (contiguous permuted 16), no twiddle ----
  {
    const int g = t >> 4, j1 = t & 15;
    const int base = (g << 8) + (j1 << 4);
#pragma unroll
    for (int m2 = 0; m2 < 16; ++m2) r[m2] = Z[base + (m2 ^ j1)];
    fft16<-1, false>(r);
#pragma unroll
    for (int j2 = 0; j2 < 16; ++j2) Z[base + (j2 ^ j1)] = r[POS(j2)];
  }
  __syncthreads();

  // ---- pointwise: position-indexed pairs, conflict-free & coalesced table ----
  {
    const int c = t & 15;
    const float4* tpz = (const float4*)(tab + (size_t)h * kTabIters * 256 * 4);
#pragma unroll
    for (int i = 0; i <= 8; ++i) {
      const float4* tp = tpz + ((i << 8) + t) * 2;
      float4 q0 = tp[0], q1 = tp[1];
      if (i == 0 && t == 0) {
        cplx Z0 = Z[0];
        cplx o; o.x = q0.x * Z0.x + q0.y * Z0.y; o.y = q0.z * Z0.x + q0.w * Z0.y;
        Z[0] = o;
      } else if (i == 0 && t == 8) {
        cplx f; f.x = q0.x; f.y = q0.y;
        Z[8] = pk_cmul(f, Z[8]);  // SW(8)=8, bin 2048
      } else if ((i >= 1 && i <= 7) || c < 8) {
        int p = (i << 8) + t;
        int p2 = (i == 0) ? ((t < 16) ? (16 - t) : (271 - t))
                          : (((16 - i) << 8) + (255 - t));
        int sp = SW(p), sp2 = SW(p2);
        cplx Zk = Z[sp], Zmk = Z[sp2];
        cplx e0 = {q0.x, q0.y}, e1 = {q0.z, q0.w};
        cplx e2 = {q1.x, q1.y}, e3 = {q1.z, q1.w};
        cplx cZk = {Zk.x, -Zk.y}, cZmk = {Zmk.x, -Zmk.y};
        Z[sp] = pk_add(pk_cmul(e0, Zk), pk_cmul(e1, cZmk));
        Z[sp2] = pk_add(pk_cmul(e2, cZk), pk_cmul(e3, Zmk));
      }
    }
  }
  __syncthreads();

  // ---- I1: IDFT16 over j2 (contiguous permuted 16), table twiddle ----
  {
    const int k1 = t >> 4, j1 = t & 15;
    const int base = (k1 << 8) + (j1 << 4);
#pragma unroll
    for (int p = 1; p < 16; ++p) tw[p - 1] = twI1s[((p - 1) << 4) + j1];
#pragma unroll
    for (int j2 = 0; j2 < 16; ++j2) r[j2] = Z[base + (j2 ^ j1)];
    fft16<1, false>(r);
#pragma unroll
    for (int p = 1; p < 16; ++p) r[POS(p)] = pk_cmul(r[POS(p)], tw[p - 1]);
#pragma unroll
    for (int m2 = 0; m2 < 16; ++m2) Z[base + (m2 ^ j1)] = r[POS(m2)];
  }
  __syncthreads();

  // ---- I2: IDFT16 over j1 (stride 16), table twiddle e^{+2pi i k1*(m1*16+m2)/4096} ----
  {
    const int k1 = t >> 4, m2 = t & 15;
    cplx twb[16];
#pragma unroll
    for (int m1 = 0; m1 < 16; ++m1) twb[m1] = twI2[(m1 << 8) + t];
#pragma unroll
    for (int j1 = 0; j1 < 16; ++j1) r[j1] = Z[(k1 << 8) + (j1 << 4) + (m2 ^ j1)];
    fft16<1, false>(r);
#pragma unroll
    for (int m1 = 0; m1 < 16; ++m1) r[POS(m1)] = pk_cmul(r[POS(m1)], twb[m1]);
#pragma unroll
    for (int m1 = 0; m1 < 16; ++m1) Z[(k1 << 8) + (m1 << 4) + (m2 ^ m1)] = r[POS(m1)];
  }
  __syncthreads();

  // ---- I3: IDFT16 over k1 (stride 256), bf16x2 coalesced global store ----
  {
    cplx* Zb = &Z[swt];
#pragma unroll
    for (int k1 = 0; k1 < 16; ++k1) r[k1] = Zb[k1 << 8];
    fft16<1, false>(r);
#pragma unroll
    for (int n1 = 0; n1 < 8; ++n1) {
      cplx v = r[POS(n1)];
      zrow[(n1 << 8) + t] = pkbf(v.x, v.y);
    }
  }
}

// ---------- pass 3: transpose back z (B,C,L/2) -> out (B,L,C) + mix ----------
__global__ __launch_bounds__(256) void mix_out(const unsigned* __restrict__ zin,
                                               const float* __restrict__ x,
                                               const float* __restrict__ mix_logit,
                                               float* __restrict__ outp) {
  __shared__ float T[64][33];
  const int b = blockIdx.z;
  const int l0 = blockIdx.x * 64;
  const int c0 = blockIdx.y * 32;
  const int h = c0 >> 6;
  const float ml = mix_logit[h];
  const float mix = 1.0f / (1.0f + __expf(-ml));
  const float omix = 1.0f - mix;
  const unsigned* yb = zin + (size_t)b * kC * kN2;
  const float* xb = x + (size_t)b * kL * kC;
  float* ob = outp + (size_t)b * kL * kC;
  const int tx = threadIdx.x & 31, ty = threadIdx.x >> 5;
  const int n0 = l0 >> 1;
#pragma unroll
  for (int i = 0; i < 32; i += 8) {
    int c = ty + i;
    unsigned d = yb[(size_t)(c0 + c) * kN2 + n0 + tx];
    T[2 * tx][c] = __uint_as_float(d << 16);
    T[2 * tx + 1][c] = __uint_as_float(d & 0xffff0000u);
  }
  __syncthreads();
#pragma unroll
  for (int i = 0; i < 64; i += 8) {
    int l = ty + i;
    size_t idx = (size_t)(l0 + l) * kC + c0 + tx;
    ob[idx] = mix * T[l][tx] + omix * xb[idx];
  }
}

// ---------- fallback (round-1 single kernel) if ws is too small ----------
__global__ __launch_bounds__(NTH) void fftconv_fallback(
    const float* __restrict__ x, const float* __restrict__ log_amp,
    const float* __restrict__ log_decay, const float* __restrict__ mix_logit,
    float* __restrict__ out) {
  __shared__ float2 Z[kZPad];
  const int row = blockIdx.x;
  const int d = row & (kD - 1);
  const int h = (row >> 6) & (kH - 1);
  const int b = row >> 10;
  const int t = threadIdx.x;
  const size_t rowoff = (size_t)b * kL * kC + (size_t)h * kD + (size_t)d;
  const float* xrow = x + rowoff;
  float* orow = out + rowoff;

  const float av = log_amp[h];
  const float dv = log_decay[h];
  const float amp = (av > 20.f) ? av : log1pf(__expf(av));
  const float dec = ((dv > 20.f) ? dv : log1pf(__expf(dv))) + 1e-4f;
  const float ampS = amp * (1.0f / (float)kM);
  const float ml = mix_logit[h];
  const float mix = 1.0f / (1.0f + __expf(-ml));
  const float omix = 1.0f - mix;

  for (int i = 0; i < kM / NTH; ++i) {
    int n = t + i * NTH;
    float2 z;
    if (n < kL / 2) {
      z.x = xrow[(size_t)(2 * n) * kC];
      z.y = xrow[(size_t)(2 * n + 1) * kC];
    } else {
      z = make_float2(0.f, 0.f);
    }
    Z[IDX(n)] = z;
  }
  __syncthreads();

  for (int Ls = kM; Ls >= 4; Ls >>= 2) {
    const int q = Ls >> 2;
    const float wstep = -6.283185307179586f / (float)Ls;
    for (int i = 0; i < kM / 4 / NTH; ++i) {
      int bt = t + i * NTH;
      int jj = bt & (q - 1);
      int base = ((bt - jj) << 2) + jj;
      float2 a = Z[IDX(base)], bb = Z[IDX(base + q)];
      float2 c = Z[IDX(base + 2 * q)], dd = Z[IDX(base + 3 * q)];
      float2 t0 = cadd(a, c), t1 = csub(a, c), t2 = cadd(bb, dd), t3 = csub(bb, dd);
      float2 u0 = cadd(t0, t2), u2 = csub(t0, t2);
      float2 it3 = cmuli(t3);
      float2 u1 = csub(t1, it3), u3 = cadd(t1, it3);
      float sn, cs;
      __sincosf(wstep * (float)jj, &sn, &cs);
      float2 w1 = make_float2(cs, sn);
      float2 w2 = cmul(w1, w1);
      float2 w3 = cmul(w2, w1);
      Z[IDX(base)] = u0;
      Z[IDX(base + q)] = cmul(u1, w1);
      Z[IDX(base + 2 * q)] = cmul(u2, w2);
      Z[IDX(base + 3 * q)] = cmul(u3, w3);
    }
    __syncthreads();
  }

  for (int i = 0; i <= kM / 2 / NTH; ++i) {
    int k = t + i * NTH;
    if (k > kM / 2) continue;
    if (k == 0) {
      float2 Z0 = Z[IDX(0)];
      float X0 = Z0.x + Z0.y;
      float XM = Z0.x - Z0.y;
      float2 f0 = filt_val(0.f, ampS, dec);
      float2 fM = filt_val((float)kM, ampS, dec);
      float Y0 = X0 * f0.x;
      float YM = XM * fM.x;
      Z[IDX(0)] = make_float2(0.5f * (Y0 + YM), 0.5f * (Y0 - YM));
    } else if (k == kM / 2) {
      unsigned p = dr4(kM / 2);
      float2 Zk = Z[IDX(p)];
      float2 f = filt_val((float)(kM / 2), ampS, dec);
      float2 Y = cmul(cconj(Zk), f);
      Z[IDX(p)] = cconj(Y);
    } else {
      unsigned pk = dr4((unsigned)k), pmk = dr4((unsigned)(kM - k));
      float2 Zk = Z[IDX(pk)], Zmk = Z[IDX(pmk)];
      float2 A = cscale(cadd(Zk, cconj(Zmk)), 0.5f);
      float2 Bv = cscale(csub(Zk, cconj(Zmk)), 0.5f);
      float sn, cs;
      __sincosf(-3.14159265358979323846f * (float)k / (float)kM, &sn, &cs);
      float2 tw = make_float2(cs, sn);
      float2 P = cmuli(cmul(tw, Bv));
      float2 Xk = csub(A, P);
      float2 Xmk = cconj(cadd(A, P));
      float2 Yk = cmul(Xk, filt_val((float)k, ampS, dec));
      float2 Ymk = cmul(Xmk, filt_val((float)(kM - k), ampS, dec));
      float2 Ev = cscale(cadd(Yk, cconj(Ymk)), 0.5f);
      float2 Ov = cscale(cmul(cconj(tw), csub(Yk, cconj(Ymk))), 0.5f);
      float2 iO = cmuli(Ov);
      Z[IDX(pk)] = cadd(Ev, iO);
      Z[IDX(pmk)] = cconj(csub(Ev, iO));
    }
  }
  __syncthreads();

  for (int Ls = 4; Ls <= kM; Ls <<= 2) {
    const int q = Ls >> 2;
    const float wstep = 6.283185307179586f / (float)Ls;
    for (int i = 0; i < kM / 4 / NTH; ++i) {
      int bt = t + i * NTH;
      int jj = bt & (q - 1);
      int base = ((bt - jj) << 2) + jj;
      float sn, cs;
      __sincosf(wstep * (float)jj, &sn, &cs);
      float2 w1 = make_float2(cs, sn);
      float2 w2 = cmul(w1, w1);
      float2 w3 = cmul(w2, w1);
      float2 a = Z[IDX(base)];
      float2 bb = cmul(Z[IDX(base + q)], w1);
      float2 c = cmul(Z[IDX(base + 2 * q)], w2);
      float2 dd = cmul(Z[IDX(base + 3 * q)], w3);
      float2 s0 = cadd(a, c), s1 = csub(a, c), s2 = cadd(bb, dd), s3 = csub(bb, dd);
      float2 is3 = cmuli(s3);
      Z[IDX(base)] = cadd(s0, s2);
      Z[IDX(base + 2 * q)] = csub(s0, s2);
      Z[IDX(base + q)] = cadd(s1, is3);
      Z[IDX(base + 3 * q)] = csub(s1, is3);
    }
    __syncthreads();
  }

  for (int i = 0; i < kL / 2 / NTH; ++i) {
    int n = t + i * NTH;
    float2 w = Z[IDX(n)];
    size_t i0 = (size_t)(2 * n) * kC;
    float x0 = xrow[i0];
    float x1 = xrow[i0 + kC];
    orow[i0] = mix * w.x + omix * x0;
    orow[i0 + kC] = mix * w.y + omix * x1;
  }
}

extern "C" void kernel_launch(void* const* d_in, const int* in_sizes, int n_in,
                              void* d_out, int out_size, void* d_ws, size_t ws_size,
                              hipStream_t stream) {
  const float* x = (const float*)d_in[0];
  const float* la = (const float*)d_in[1];
  const float* ld = (const float*)d_in[2];
  const float* ml = (const float*)d_in[3];
  float* out = (float*)d_out;
  const size_t zbytes = (size_t)kB * kC * kN2 * sizeof(unsigned);               // 32 MiB
  const size_t tabbytes = (size_t)kH * kTabIters * 256 * 4 * sizeof(float2);    // ~1.1 MiB
  const size_t twbytes = (size_t)(31 * 256 + 480) * sizeof(float2);             // ~66 KiB
  if (ws_size >= zbytes + tabbytes + twbytes) {
    unsigned* wsz = (unsigned*)d_ws;
    float2* tab = (float2*)((char*)d_ws + zbytes);
    float2* tw = (float2*)((char*)d_ws + zbytes + tabbytes);
    const cplx* twF1 = (const cplx*)tw;
    const cplx* twI2 = (const cplx*)(tw + 15 * 256);
    const cplx* twF2s = (const cplx*)(tw + 31 * 256);
    const cplx* twI1s = (const cplx*)(tw + 31 * 256 + 240);
    build_table<<<dim3(kTabIters, kH), dim3(256), 0, stream>>>(la, ld, tab);
    build_tw<<<dim3(16), dim3(256), 0, stream>>>(tw);
    transpose_fwd<<<dim3(kL / 64, kC / 32, kB), dim3(256), 0, stream>>>(x, wsz);
    fft_rows<<<dim3(kB * kC), dim3(NTH), 0, stream>>>(wsz, tab, twF1, twI2, twF2s, twI1s);
    mix_out<<<dim3(kL / 64, kC / 32, kB), dim3(256), 0, stream>>>(wsz, x, ml, out);
  } else {
    fftconv_fallback<<<dim3(kB * kC), dim3(NTH), 0, stream>>>(x, la, ld, ml, out);
  }
}

// Round 8
// 97.405 us; speedup vs baseline: 1.4339x; 1.1152x over previous
//
#include <hip/hip_runtime.h>
#include <math.h>

namespace {
constexpr int kB = 4;
constexpr int kL = 4096;
constexpr int kH = 16;
constexpr int kD = 64;
constexpr int kC = kH * kD;       // 1024 channels
constexpr int kM = 4096;          // complex FFT length (rfft of 8192 via packing)
constexpr int kN2 = kL / 2;       // 2048 packed complex samples per row
constexpr int NTH = 256;
constexpr int kTabIters = 9;      // pointwise iterations 0..8

// ---------------- scalar complex helpers (aux kernels) ----------------
__device__ __forceinline__ float2 cmul(float2 a, float2 b) {
  return make_float2(a.x * b.x - a.y * b.y, a.x * b.y + a.y * b.x);
}
__device__ __forceinline__ float2 cadd(float2 a, float2 b) { return make_float2(a.x + b.x, a.y + b.y); }
__device__ __forceinline__ float2 csub(float2 a, float2 b) { return make_float2(a.x - b.x, a.y - b.y); }
__device__ __forceinline__ float2 cconj(float2 a) { return make_float2(a.x, -a.y); }
__device__ __forceinline__ float2 cmuli(float2 a) { return make_float2(-a.y, a.x); }  // i*a
__device__ __forceinline__ float2 cscale(float2 a, float s) { return make_float2(a.x * s, a.y * s); }

// ---------------- packed-FP32 complex helpers (fft_rows) ----------------
typedef float cplx __attribute__((ext_vector_type(2)));

__device__ __forceinline__ cplx pk_add(cplx a, cplx b) {
  cplx r;
  asm("v_pk_add_f32 %0, %1, %2" : "=v"(r) : "v"(a), "v"(b));
  return r;
}
__device__ __forceinline__ cplx pk_sub(cplx a, cplx b) {
  cplx r;
  asm("v_pk_add_f32 %0, %1, %2 neg_lo:[0,1] neg_hi:[0,1]" : "=v"(r) : "v"(a), "v"(b));
  return r;
}
// a + i*b = (a.x - b.y, a.y + b.x)
__device__ __forceinline__ cplx pk_addpi(cplx a, cplx b) {
  cplx r;
  asm("v_pk_add_f32 %0, %1, %2 op_sel:[0,1] op_sel_hi:[1,0] neg_lo:[0,1]" : "=v"(r) : "v"(a), "v"(b));
  return r;
}
// a - i*b = (a.x + b.y, a.y - b.x)
__device__ __forceinline__ cplx pk_addmi(cplx a, cplx b) {
  cplx r;
  asm("v_pk_add_f32 %0, %1, %2 op_sel:[0,1] op_sel_hi:[1,0] neg_hi:[0,1]" : "=v"(r) : "v"(a), "v"(b));
  return r;
}
// complex multiply: 2 VOP3P ops
__device__ __forceinline__ cplx pk_cmul(cplx a, cplx b) {
  cplx t, r;
  asm("v_pk_mul_f32 %0, %1, %2 op_sel:[0,0] op_sel_hi:[0,1]" : "=v"(t) : "v"(a), "v"(b));
  asm("v_pk_fma_f32 %0, %1, %2, %3 op_sel:[1,1,0] op_sel_hi:[1,0,1] neg_lo:[0,1,0]"
      : "=v"(r) : "v"(a), "v"(b), "v"(t));
  return r;
}

// bf16x2 pack (RNE) / unpack
__device__ __forceinline__ unsigned pkbf(float lo, float hi) {
  unsigned r;
  asm("v_cvt_pk_bf16_f32 %0, %1, %2" : "=v"(r) : "v"(lo), "v"(hi));
  return r;
}
__device__ __forceinline__ cplx unpk(unsigned d) {
  cplx r;
  r.x = __uint_as_float(d << 16);
  r.y = __uint_as_float(d & 0xffff0000u);
  return r;
}

// base-4 digit reversal of a 12-bit index (fallback kernel only)
__device__ __forceinline__ unsigned dr4(unsigned p) {
  unsigned r = __brev(p) >> 20;
  return ((r & 0x555u) << 1) | ((r >> 1) & 0x555u);
}
// base-16 digit reversal of a 12-bit index (involution)
__device__ __forceinline__ unsigned dr16(unsigned p) {
  return ((p & 15u) << 8) | (p & 0xF0u) | (p >> 8);
}
// XOR LDS swizzle (cplx index space): phys = p ^ ((p>>4)&15)
__device__ __forceinline__ int SW(int i) { return i ^ ((i >> 4) & 15); }
// after in-register DFT16, X[k] lives at register slot POS(k)
#define POS(k) ((((k) & 3) << 2) | ((k) >> 2))

// fallback-kernel padding
__device__ __forceinline__ int IDX(int i) { return i + (i >> 4); }
constexpr int kZPad = kM + (kM >> 4);

// depth-4 twiddle power tree: W1..W15 = w^1..w^15
#define TW_TREE(w)                                                            \
  cplx W1 = (w), W2 = pk_cmul(W1, W1), W4 = pk_cmul(W2, W2),                  \
       W8 = pk_cmul(W4, W4);                                                  \
  cplx W3 = pk_cmul(W2, W1), W5 = pk_cmul(W4, W1), W6 = pk_cmul(W4, W2),      \
       W7 = pk_cmul(W4, W3);                                                  \
  cplx W9 = pk_cmul(W8, W1), W10 = pk_cmul(W8, W2), W11 = pk_cmul(W8, W3),    \
       W12 = pk_cmul(W8, W4);                                                 \
  cplx W13 = pk_cmul(W8, W5), W14 = pk_cmul(W8, W6), W15 = pk_cmul(W8, W7);

#define TW_APPLY(r)                                                           \
  r[POS(1)] = pk_cmul(r[POS(1)], W1);   r[POS(2)] = pk_cmul(r[POS(2)], W2);   \
  r[POS(3)] = pk_cmul(r[POS(3)], W3);   r[POS(4)] = pk_cmul(r[POS(4)], W4);   \
  r[POS(5)] = pk_cmul(r[POS(5)], W5);   r[POS(6)] = pk_cmul(r[POS(6)], W6);   \
  r[POS(7)] = pk_cmul(r[POS(7)], W7);   r[POS(8)] = pk_cmul(r[POS(8)], W8);   \
  r[POS(9)] = pk_cmul(r[POS(9)], W9);   r[POS(10)] = pk_cmul(r[POS(10)], W10);\
  r[POS(11)] = pk_cmul(r[POS(11)], W11); r[POS(12)] = pk_cmul(r[POS(12)], W12);\
  r[POS(13)] = pk_cmul(r[POS(13)], W13); r[POS(14)] = pk_cmul(r[POS(14)], W14);\
  r[POS(15)] = pk_cmul(r[POS(15)], W15);

// shifted tree: B[k] = b0 * w^k, k = 0..15, depth ~4
#define TWS_TREE(b0, w)                                                       \
  cplx P2 = pk_cmul(w, w), P4 = pk_cmul(P2, P2), P8 = pk_cmul(P4, P4);        \
  cplx B0 = (b0), B1 = pk_cmul(b0, w), B2 = pk_cmul(B0, P2),                  \
       B3 = pk_cmul(B1, P2);                                                  \
  cplx B4 = pk_cmul(B0, P4), B5 = pk_cmul(B1, P4), B6 = pk_cmul(B2, P4),      \
       B7 = pk_cmul(B3, P4);                                                  \
  cplx B8 = pk_cmul(B0, P8), B9 = pk_cmul(B1, P8), B10 = pk_cmul(B2, P8),     \
       B11 = pk_cmul(B3, P8);                                                 \
  cplx B12 = pk_cmul(B4, P8), B13 = pk_cmul(B5, P8), B14 = pk_cmul(B6, P8),   \
       B15 = pk_cmul(B7, P8);

#define TWS_APPLY(r)                                                          \
  r[POS(0)] = pk_cmul(r[POS(0)], B0);   r[POS(1)] = pk_cmul(r[POS(1)], B1);   \
  r[POS(2)] = pk_cmul(r[POS(2)], B2);   r[POS(3)] = pk_cmul(r[POS(3)], B3);   \
  r[POS(4)] = pk_cmul(r[POS(4)], B4);   r[POS(5)] = pk_cmul(r[POS(5)], B5);   \
  r[POS(6)] = pk_cmul(r[POS(6)], B6);   r[POS(7)] = pk_cmul(r[POS(7)], B7);   \
  r[POS(8)] = pk_cmul(r[POS(8)], B8);   r[POS(9)] = pk_cmul(r[POS(9)], B9);   \
  r[POS(10)] = pk_cmul(r[POS(10)], B10); r[POS(11)] = pk_cmul(r[POS(11)], B11);\
  r[POS(12)] = pk_cmul(r[POS(12)], B12); r[POS(13)] = pk_cmul(r[POS(13)], B13);\
  r[POS(14)] = pk_cmul(r[POS(14)], B14); r[POS(15)] = pk_cmul(r[POS(15)], B15);

// filt[k] = amp * (1 + i k)^(-dec), with 1/M ifft scale folded into ampS
__device__ __forceinline__ float2 filt_val(float k, float ampS, float dec) {
  float mag = ampS * __expf(-0.5f * dec * log1pf(k * k));
  float ph = -dec * atanf(k);
  float s, c;
  __sincosf(ph, &s, &c);
  return make_float2(mag * c, mag * s);
}

// ---- fully-unrolled 16-point DFT in registers (packed-FP32) ----
template <int S, bool HZ>
__device__ __forceinline__ void fft16(cplx r[16]) {
  constexpr float C1 = 0.92387953251128674f;
  constexpr float S1 = 0.38268343236508978f;
  constexpr float R2 = 0.70710678118654752f;
  const float sg = (float)S;
  const cplx Wa = {C1, sg * S1};
  const cplx Wb = {R2, sg * R2};
  const cplx Wc = {S1, sg * C1};
  const cplx Wd = {-R2, sg * R2};
  const cplx We = {-C1, -sg * S1};
#pragma unroll
  for (int n2 = 0; n2 < 4; ++n2) {
    cplx t0, t1, t2, t3;
    if (HZ) {
      t0 = r[n2]; t1 = r[n2]; t2 = r[n2 + 4]; t3 = r[n2 + 4];
    } else {
      cplx a0 = r[n2], a1 = r[n2 + 4], a2 = r[n2 + 8], a3 = r[n2 + 12];
      t0 = pk_add(a0, a2); t1 = pk_sub(a0, a2); t2 = pk_add(a1, a3); t3 = pk_sub(a1, a3);
    }
    cplx u0 = pk_add(t0, t2);
    cplx u2 = pk_sub(t0, t2);
    cplx u1 = (S < 0) ? pk_addmi(t1, t3) : pk_addpi(t1, t3);
    cplx u3 = (S < 0) ? pk_addpi(t1, t3) : pk_addmi(t1, t3);
    if (n2 == 0) { r[0] = u0; r[4] = u1; r[8] = u2; r[12] = u3; }
    if (n2 == 1) { r[1] = u0; r[5] = pk_cmul(u1, Wa); r[9] = pk_cmul(u2, Wb); r[13] = pk_cmul(u3, Wc); }
    if (n2 == 2) {
      r[2] = u0; r[6] = pk_cmul(u1, Wb);
      cplx m;
      if (S < 0) { m.x = u2.y; m.y = -u2.x; } else { m.x = -u2.y; m.y = u2.x; }
      r[10] = m;
      r[14] = pk_cmul(u3, Wd);
    }
    if (n2 == 3) { r[3] = u0; r[7] = pk_cmul(u1, Wc); r[11] = pk_cmul(u2, Wd); r[15] = pk_cmul(u3, We); }
  }
#pragma unroll
  for (int s = 0; s < 4; ++s) {
    cplx b0 = r[4 * s], b1 = r[4 * s + 1], b2 = r[4 * s + 2], b3 = r[4 * s + 3];
    cplx t0 = pk_add(b0, b2), t1 = pk_sub(b0, b2), t2 = pk_add(b1, b3), t3 = pk_sub(b1, b3);
    r[4 * s] = pk_add(t0, t2);
    r[4 * s + 2] = pk_sub(t0, t2);
    r[4 * s + 1] = (S < 0) ? pk_addmi(t1, t3) : pk_addpi(t1, t3);
    r[4 * s + 3] = (S < 0) ? pk_addpi(t1, t3) : pk_addmi(t1, t3);
  }
}

// pointwise pair map (verified algebra), used only by build_table
__device__ __forceinline__ void pw_pair(float2 Zk, float2 Zmk, int k, float ampS, float dec,
                                        float2* Wk, float2* Wmk) {
  float2 A = cscale(cadd(Zk, cconj(Zmk)), 0.5f);
  float2 Bv = cscale(csub(Zk, cconj(Zmk)), 0.5f);
  float sn, cs;
  __sincosf(-3.14159265358979323846f * (float)k / (float)kM, &sn, &cs);
  float2 tw = make_float2(cs, sn);
  float2 P = cmuli(cmul(tw, Bv));
  float2 Xk = csub(A, P);
  float2 Xmk = cconj(cadd(A, P));
  float2 Yk = cmul(Xk, filt_val((float)k, ampS, dec));
  float2 Ymk = cmul(Xmk, filt_val((float)(kM - k), ampS, dec));
  float2 Ev = cscale(cadd(Yk, cconj(Ymk)), 0.5f);
  float2 Ov = cscale(cmul(cconj(tw), csub(Yk, cconj(Ymk))), 0.5f);
  float2 iO = cmuli(Ov);
  *Wk = cadd(Ev, iO);
  *Wmk = cconj(csub(Ev, iO));
}
}  // namespace

// ---------- pass 0: coefficient table keyed by (h, iter, lane) ----------
__global__ __launch_bounds__(256) void build_table(const float* __restrict__ la,
                                                   const float* __restrict__ ld,
                                                   float2* __restrict__ tab) {
  const int i = blockIdx.x;   // 0..8
  const int h = blockIdx.y;
  const int t = threadIdx.x;  // 0..255
  float av = la[h], dv = ld[h];
  float amp = (av > 20.f) ? av : log1pf(__expf(av));
  float dec = ((dv > 20.f) ? dv : log1pf(__expf(dv))) + 1e-4f;
  float ampS = amp * (1.0f / (float)kM);
  float2 e0 = make_float2(0.f, 0.f), e1 = e0, e2 = e0, e3 = e0;
  const int c = t & 15;
  if (i == 0 && t == 0) {
    float F0 = filt_val(0.f, ampS, dec).x;
    float FM = filt_val((float)kM, ampS, dec).x;
    e0 = make_float2(0.5f * (F0 + FM), 0.5f * (F0 - FM));
    e1 = make_float2(0.5f * (F0 - FM), 0.5f * (F0 + FM));
  } else if (i == 0 && t == 8) {
    e0 = cconj(filt_val((float)(kM / 2), ampS, dec));  // bin 2048 single coeff
  } else if ((i >= 1 && i <= 7) || c < 8) {
    int p = (i << 8) + t;
    int k = (int)dr16((unsigned)p);
    float2 a, b, g, d;
    pw_pair(make_float2(1.f, 0.f), make_float2(0.f, 0.f), k, ampS, dec, &a, &g);
    pw_pair(make_float2(0.f, 0.f), make_float2(1.f, 0.f), k, ampS, dec, &b, &d);
    e0 = a; e1 = b; e2 = g; e3 = d;
  }
  float2* e = tab + ((size_t)(h * kTabIters + i) * 256 + t) * 4;
  e[0] = e0; e[1] = e1; e[2] = e2; e[3] = e3;
}

// ---------- pass 1: transpose + pack x (B,L,C) -> z bf16x2 (B,C,L/2) ----------
__global__ __launch_bounds__(256) void transpose_fwd(const float* __restrict__ in,
                                                     unsigned* __restrict__ zout) {
  __shared__ float T[64][33];
  const int b = blockIdx.z;
  const int l0 = blockIdx.x * 64;
  const int c0 = blockIdx.y * 32;
  const float* ib = in + (size_t)b * kL * kC;
  unsigned* ob = zout + (size_t)b * kC * kN2;
  const int tx = threadIdx.x & 31, ty = threadIdx.x >> 5;
#pragma unroll
  for (int i = 0; i < 64; i += 8)
    T[ty + i][tx] = ib[(size_t)(l0 + ty + i) * kC + c0 + tx];
  __syncthreads();
  const int n0 = l0 >> 1;
#pragma unroll
  for (int i = 0; i < 32; i += 8) {
    int c = ty + i;
    ob[(size_t)(c0 + c) * kN2 + n0 + tx] = pkbf(T[2 * tx][c], T[2 * tx + 1][c]);
  }
}

// ---------- pass 2: per-row FFT conv (16^3 register radix-16, packed math) ----------
__global__ __launch_bounds__(NTH) void fft_rows(unsigned* __restrict__ zio,
                                                const float2* __restrict__ tab) {
  __shared__ cplx Z[kM];  // 32 KB
  const int row = blockIdx.x;  // b*1024 + c
  const int h = (row >> 6) & (kH - 1);
  const int t = threadIdx.x;
  unsigned* zrow = zio + (size_t)row * kN2;

  cplx r[16];
  const int swt = t ^ ((t >> 4) & 15);

  // ---- F1: global load (bf16x2 dwords), DFT16 over n1, twiddle W4096^{t*k1} ----
  {
    unsigned din[8];
#pragma unroll
    for (int j = 0; j < 8; ++j) din[j] = zrow[t + (j << 8)];
#pragma unroll
    for (int j = 0; j < 8; ++j) r[j] = unpk(din[j]);
    fft16<-1, true>(r);
    float sn, cs;
    __sincosf(-6.283185307179586f * (float)t / 4096.f, &sn, &cs);
    cplx w = {cs, sn};
    TW_TREE(w);
    TW_APPLY(r);
    cplx* Zb = &Z[swt];
#pragma unroll
    for (int k1 = 0; k1 < 16; ++k1) Zb[k1 << 8] = r[POS(k1)];
  }
  __syncthreads();

  // ---- F2: DFT16 over m1 (stride 16), twiddle W256^{m2*j1} ----
  {
    const int g = t >> 4, m2 = t & 15;
    const int base = g << 8;
#pragma unroll
    for (int m1 = 0; m1 < 16; ++m1) r[m1] = Z[base + (m1 << 4) + (m2 ^ m1)];
    fft16<-1, false>(r);
    float sn, cs;
    __sincosf(-6.283185307179586f * (float)m2 / 256.f, &sn, &cs);
    cplx w = {cs, sn};
    TW_TREE(w);
    TW_APPLY(r);
#pragma unroll
    for (int j1 = 0; j1 < 16; ++j1) Z[base + (j1 << 4) + (m2 ^ j1)] = r[POS(j1)];
  }
  __syncthreads();

  // ---- F3: DFT16 over m2 (contiguous permuted 16), no twiddle ----
  {
    const int g = t >> 4, j1 = t & 15;
    const int base = (g << 8) + (j1 << 4);
#pragma unroll
    for (int m2 = 0; m2 < 16; ++m2) r[m2] = Z[base + (m2 ^ j1)];
    fft16<-1, false>(r);
#pragma unroll
    for (int j2 = 0; j2 < 16; ++j2) Z[base + (j2 ^ j1)] = r[POS(j2)];
  }
  __syncthreads();

  // ---- pointwise: position-indexed pairs, conflict-free & coalesced table ----
  {
    const int c = t & 15;
    const float4* tpz = (const float4*)(tab + (size_t)h * kTabIters * 256 * 4);
#pragma unroll
    for (int i = 0; i <= 8; ++i) {
      const float4* tp = tpz + ((i << 8) + t) * 2;
      float4 q0 = tp[0], q1 = tp[1];
      if (i == 0 && t == 0) {
        cplx Z0 = Z[0];
        cplx o; o.x = q0.x * Z0.x + q0.y * Z0.y; o.y = q0.z * Z0.x + q0.w * Z0.y;
        Z[0] = o;
      } else if (i == 0 && t == 8) {
        cplx f; f.x = q0.x; f.y = q0.y;
        Z[8] = pk_cmul(f, Z[8]);  // SW(8)=8, bin 2048
      } else if ((i >= 1 && i <= 7) || c < 8) {
        int p = (i << 8) + t;
        int p2 = (i == 0) ? ((t < 16) ? (16 - t) : (271 - t))
                          : (((16 - i) << 8) + (255 - t));
        int sp = SW(p), sp2 = SW(p2);
        cplx Zk = Z[sp], Zmk = Z[sp2];
        cplx e0 = {q0.x, q0.y}, e1 = {q0.z, q0.w};
        cplx e2 = {q1.x, q1.y}, e3 = {q1.z, q1.w};
        cplx cZk = {Zk.x, -Zk.y}, cZmk = {Zmk.x, -Zmk.y};
        Z[sp] = pk_add(pk_cmul(e0, Zk), pk_cmul(e1, cZmk));
        Z[sp2] = pk_add(pk_cmul(e2, cZk), pk_cmul(e3, Zmk));
      }
    }
  }
  __syncthreads();

  // ---- I1: IDFT16 over j2 (contiguous permuted 16), twiddle e^{+2pi i j1*m2/256} ----
  {
    const int k1 = t >> 4, j1 = t & 15;
    const int base = (k1 << 8) + (j1 << 4);
#pragma unroll
    for (int j2 = 0; j2 < 16; ++j2) r[j2] = Z[base + (j2 ^ j1)];
    fft16<1, false>(r);
    float sn, cs;
    __sincosf(6.283185307179586f * (float)j1 / 256.f, &sn, &cs);
    cplx w = {cs, sn};
    TW_TREE(w);
    TW_APPLY(r);
#pragma unroll
    for (int m2 = 0; m2 < 16; ++m2) Z[base + (m2 ^ j1)] = r[POS(m2)];
  }
  __syncthreads();

  // ---- I2: IDFT16 over j1 (stride 16), twiddle e^{+2pi i k1*(m1*16+m2)/4096} ----
  {
    const int k1 = t >> 4, m2 = t & 15;
#pragma unroll
    for (int j1 = 0; j1 < 16; ++j1) r[j1] = Z[(k1 << 8) + (j1 << 4) + (m2 ^ j1)];
    fft16<1, false>(r);
    float sn, cs;
    __sincosf(6.283185307179586f * (float)(k1 * m2) / 4096.f, &sn, &cs);
    cplx b0 = {cs, sn};
    __sincosf(6.283185307179586f * (float)k1 / 256.f, &sn, &cs);
    cplx w = {cs, sn};
    TWS_TREE(b0, w);
    TWS_APPLY(r);
#pragma unroll
    for (int m1 = 0; m1 < 16; ++m1) Z[(k1 << 8) + (m1 << 4) + (m2 ^ m1)] = r[POS(m1)];
  }
  __syncthreads();

  // ---- I3: IDFT16 over k1 (stride 256), bf16x2 coalesced global store ----
  {
    cplx* Zb = &Z[swt];
#pragma unroll
    for (int k1 = 0; k1 < 16; ++k1) r[k1] = Zb[k1 << 8];
    fft16<1, false>(r);
#pragma unroll
    for (int n1 = 0; n1 < 8; ++n1) {
      cplx v = r[POS(n1)];
      zrow[(n1 << 8) + t] = pkbf(v.x, v.y);
    }
  }
}

// ---------- pass 3: transpose back z (B,C,L/2) -> out (B,L,C) + mix ----------
__global__ __launch_bounds__(256) void mix_out(const unsigned* __restrict__ zin,
                                               const float* __restrict__ x,
                                               const float* __restrict__ mix_logit,
                                               float* __restrict__ outp) {
  __shared__ float T[64][33];
  const int b = blockIdx.z;
  const int l0 = blockIdx.x * 64;
  const int c0 = blockIdx.y * 32;
  const int h = c0 >> 6;
  const float ml = mix_logit[h];
  const float mix = 1.0f / (1.0f + __expf(-ml));
  const float omix = 1.0f - mix;
  const unsigned* yb = zin + (size_t)b * kC * kN2;
  const float* xb = x + (size_t)b * kL * kC;
  float* ob = outp + (size_t)b * kL * kC;
  const int tx = threadIdx.x & 31, ty = threadIdx.x >> 5;
  const int n0 = l0 >> 1;
#pragma unroll
  for (int i = 0; i < 32; i += 8) {
    int c = ty + i;
    unsigned d = yb[(size_t)(c0 + c) * kN2 + n0 + tx];
    T[2 * tx][c] = __uint_as_float(d << 16);
    T[2 * tx + 1][c] = __uint_as_float(d & 0xffff0000u);
  }
  __syncthreads();
#pragma unroll
  for (int i = 0; i < 64; i += 8) {
    int l = ty + i;
    size_t idx = (size_t)(l0 + l) * kC + c0 + tx;
    ob[idx] = mix * T[l][tx] + omix * xb[idx];
  }
}

// ---------- fallback (round-1 single kernel) if ws is too small ----------
__global__ __launch_bounds__(NTH) void fftconv_fallback(
    const float* __restrict__ x, const float* __restrict__ log_amp,
    const float* __restrict__ log_decay, const float* __restrict__ mix_logit,
    float* __restrict__ out) {
  __shared__ float2 Z[kZPad];
  const int row = blockIdx.x;
  const int d = row & (kD - 1);
  const int h = (row >> 6) & (kH - 1);
  const int b = row >> 10;
  const int t = threadIdx.x;
  const size_t rowoff = (size_t)b * kL * kC + (size_t)h * kD + (size_t)d;
  const float* xrow = x + rowoff;
  float* orow = out + rowoff;

  const float av = log_amp[h];
  const float dv = log_decay[h];
  const float amp = (av > 20.f) ? av : log1pf(__expf(av));
  const float dec = ((dv > 20.f) ? dv : log1pf(__expf(dv))) + 1e-4f;
  const float ampS = amp * (1.0f / (float)kM);
  const float ml = mix_logit[h];
  const float mix = 1.0f / (1.0f + __expf(-ml));
  const float omix = 1.0f - mix;

  for (int i = 0; i < kM / NTH; ++i) {
    int n = t + i * NTH;
    float2 z;
    if (n < kL / 2) {
      z.x = xrow[(size_t)(2 * n) * kC];
      z.y = xrow[(size_t)(2 * n + 1) * kC];
    } else {
      z = make_float2(0.f, 0.f);
    }
    Z[IDX(n)] = z;
  }
  __syncthreads();

  for (int Ls = kM; Ls >= 4; Ls >>= 2) {
    const int q = Ls >> 2;
    const float wstep = -6.283185307179586f / (float)Ls;
    for (int i = 0; i < kM / 4 / NTH; ++i) {
      int bt = t + i * NTH;
      int jj = bt & (q - 1);
      int base = ((bt - jj) << 2) + jj;
      float2 a = Z[IDX(base)], bb = Z[IDX(base + q)];
      float2 c = Z[IDX(base + 2 * q)], dd = Z[IDX(base + 3 * q)];
      float2 t0 = cadd(a, c), t1 = csub(a, c), t2 = cadd(bb, dd), t3 = csub(bb, dd);
      float2 u0 = cadd(t0, t2), u2 = csub(t0, t2);
      float2 it3 = cmuli(t3);
      float2 u1 = csub(t1, it3), u3 = cadd(t1, it3);
      float sn, cs;
      __sincosf(wstep * (float)jj, &sn, &cs);
      float2 w1 = make_float2(cs, sn);
      float2 w2 = cmul(w1, w1);
      float2 w3 = cmul(w2, w1);
      Z[IDX(base)] = u0;
      Z[IDX(base + q)] = cmul(u1, w1);
      Z[IDX(base + 2 * q)] = cmul(u2, w2);
      Z[IDX(base + 3 * q)] = cmul(u3, w3);
    }
    __syncthreads();
  }

  for (int i = 0; i <= kM / 2 / NTH; ++i) {
    int k = t + i * NTH;
    if (k > kM / 2) continue;
    if (k == 0) {
      float2 Z0 = Z[IDX(0)];
      float X0 = Z0.x + Z0.y;
      float XM = Z0.x - Z0.y;
      float2 f0 = filt_val(0.f, ampS, dec);
      float2 fM = filt_val((float)kM, ampS, dec);
      float Y0 = X0 * f0.x;
      float YM = XM * fM.x;
      Z[IDX(0)] = make_float2(0.5f * (Y0 + YM), 0.5f * (Y0 - YM));
    } else if (k == kM / 2) {
      unsigned p = dr4(kM / 2);
      float2 Zk = Z[IDX(p)];
      float2 f = filt_val((float)(kM / 2), ampS, dec);
      float2 Y = cmul(cconj(Zk), f);
      Z[IDX(p)] = cconj(Y);
    } else {
      unsigned pk = dr4((unsigned)k), pmk = dr4((unsigned)(kM - k));
      float2 Zk = Z[IDX(pk)], Zmk = Z[IDX(pmk)];
      float2 A = cscale(cadd(Zk, cconj(Zmk)), 0.5f);
      float2 Bv = cscale(csub(Zk, cconj(Zmk)), 0.5f);
      float sn, cs;
      __sincosf(-3.14159265358979323846f * (float)k / (float)kM, &sn, &cs);
      float2 tw = make_float2(cs, sn);
      float2 P = cmuli(cmul(tw, Bv));
      float2 Xk = csub(A, P);
      float2 Xmk = cconj(cadd(A, P));
      float2 Yk = cmul(Xk, filt_val((float)k, ampS, dec));
      float2 Ymk = cmul(Xmk, filt_val((float)(kM - k), ampS, dec));
      float2 Ev = cscale(cadd(Yk, cconj(Ymk)), 0.5f);
      float2 Ov = cscale(cmul(cconj(tw), csub(Yk, cconj(Ymk))), 0.5f);
      float2 iO = cmuli(Ov);
      Z[IDX(pk)] = cadd(Ev, iO);
      Z[IDX(pmk)] = cconj(csub(Ev, iO));
    }
  }
  __syncthreads();

  for (int Ls = 4; Ls <= kM; Ls <<= 2) {
    const int q = Ls >> 2;
    const float wstep = 6.283185307179586f / (float)Ls;
    for (int i = 0; i < kM / 4 / NTH; ++i) {
      int bt = t + i * NTH;
      int jj = bt & (q - 1);
      int base = ((bt - jj) << 2) + jj;
      float sn, cs;
      __sincosf(wstep * (float)jj, &sn, &cs);
      float2 w1 = make_float2(cs, sn);
      float2 w2 = cmul(w1, w1);
      float2 w3 = cmul(w2, w1);
      float2 a = Z[IDX(base)];
      float2 bb = cmul(Z[IDX(base + q)], w1);
      float2 c = cmul(Z[IDX(base + 2 * q)], w2);
      float2 dd = cmul(Z[IDX(base + 3 * q)], w3);
      float2 s0 = cadd(a, c), s1 = csub(a, c), s2 = cadd(bb, dd), s3 = csub(bb, dd);
      float2 is3 = cmuli(s3);
      Z[IDX(base)] = cadd(s0, s2);
      Z[IDX(base + 2 * q)] = csub(s0, s2);
      Z[IDX(base + q)] = cadd(s1, is3);
      Z[IDX(base + 3 * q)] = csub(s1, is3);
    }
    __syncthreads();
  }

  for (int i = 0; i < kL / 2 / NTH; ++i) {
    int n = t + i * NTH;
    float2 w = Z[IDX(n)];
    size_t i0 = (size_t)(2 * n) * kC;
    float x0 = xrow[i0];
    float x1 = xrow[i0 + kC];
    orow[i0] = mix * w.x + omix * x0;
    orow[i0 + kC] = mix * w.y + omix * x1;
  }
}

extern "C" void kernel_launch(void* const* d_in, const int* in_sizes, int n_in,
                              void* d_out, int out_size, void* d_ws, size_t ws_size,
                              hipStream_t stream) {
  const float* x = (const float*)d_in[0];
  const float* la = (const float*)d_in[1];
  const float* ld = (const float*)d_in[2];
  const float* ml = (const float*)d_in[3];
  float* out = (float*)d_out;
  const size_t zbytes = (size_t)kB * kC * kN2 * sizeof(unsigned);               // 32 MiB
  const size_t tabbytes = (size_t)kH * kTabIters * 256 * 4 * sizeof(float2);    // ~1.1 MiB
  if (ws_size >= zbytes + tabbytes) {
    unsigned* wsz = (unsigned*)d_ws;
    float2* tab = (float2*)((char*)d_ws + zbytes);
    build_table<<<dim3(kTabIters, kH), dim3(256), 0, stream>>>(la, ld, tab);
    transpose_fwd<<<dim3(kL / 64, kC / 32, kB), dim3(256), 0, stream>>>(x, wsz);
    fft_rows<<<dim3(kB * kC), dim3(NTH), 0, stream>>>(wsz, tab);
    mix_out<<<dim3(kL / 64, kC / 32, kB), dim3(256), 0, stream>>>(wsz, x, ml, out);
  } else {
    fftconv_fallback<<<dim3(kB * kC), dim3(NTH), 0, stream>>>(x, la, ld, ml, out);
  }
}